// Round 3
// baseline (772.009 us; speedup 1.0000x reference)
//
#include <hip/hip_runtime.h>
#include <math.h>

// Problem constants
#define kN 50000
#define kE 800000
#define kM 4
#define kH 4
#define kC 32
#define kIN 256
#define kD 128   // kH*kC

// ---------------------------------------------------------------------------
// zero scratch
__global__ void k_zero(int* __restrict__ p, int n) {
    int i = blockIdx.x * blockDim.x + threadIdx.x;
    if (i < n) p[i] = 0;
}

__device__ __forceinline__ unsigned int f2bf_pack(float a, float b) {
    unsigned ua = __float_as_uint(a);
    ua += 0x7fffu + ((ua >> 16) & 1u);          // RNE
    unsigned ub = __float_as_uint(b);
    ub += 0x7fffu + ((ub >> 16) & 1u);
    return (ua >> 16) | (ub & 0xffff0000u);
}

// ---------------------------------------------------------------------------
// h[n][128] = relu(feats[n][256] @ W[256][128] + b); also emit bf16 copy h16
__global__ __launch_bounds__(256) void k_gemm(const float* __restrict__ feats,
                                              const float* __restrict__ W,
                                              const float* __restrict__ b,
                                              float* __restrict__ h,
                                              unsigned short* __restrict__ h16) {
    __shared__ float fr[64][68];    // [row][k], pad to break bank conflicts
    __shared__ float wc[64][128];   // [k][col]
    const int t = threadIdx.x;
    const int rowbase = blockIdx.x * 64;
    const int tr4 = (t >> 4) * 4;   // rows tr4..tr4+3
    const int tc = t & 15;          // cols tc*4..+3 and 64+tc*4..+3

    float acc[4][8];
#pragma unroll
    for (int i = 0; i < 4; i++)
#pragma unroll
        for (int j = 0; j < 8; j++) acc[i][j] = 0.f;

    for (int kc = 0; kc < kIN; kc += 64) {
        {
            const int row = t >> 4;   // 0..15
            const int k4 = t & 15;    // 0..15
#pragma unroll
            for (int i = 0; i < 4; i++) {
                const int r = row + i * 16;
                const int rg = rowbase + r;
                float4 v = make_float4(0.f, 0.f, 0.f, 0.f);
                if (rg < kN)
                    v = *reinterpret_cast<const float4*>(feats + rg * kIN + kc + k4 * 4);
                *reinterpret_cast<float4*>(&fr[r][k4 * 4]) = v;
            }
        }
#pragma unroll
        for (int i = 0; i < 8; i++) {
            const int v4 = t + i * 256;
            const int kk = v4 >> 5;
            const int c4 = v4 & 31;
            *reinterpret_cast<float4*>(&wc[kk][c4 * 4]) =
                *reinterpret_cast<const float4*>(W + (size_t)(kc + kk) * kD + c4 * 4);
        }
        __syncthreads();

#pragma unroll 8
        for (int k = 0; k < 64; k++) {
            const float a0 = fr[tr4 + 0][k];
            const float a1 = fr[tr4 + 1][k];
            const float a2 = fr[tr4 + 2][k];
            const float a3 = fr[tr4 + 3][k];
            const float4 w0 = *reinterpret_cast<const float4*>(&wc[k][tc * 4]);
            const float4 w1 = *reinterpret_cast<const float4*>(&wc[k][64 + tc * 4]);
            acc[0][0] += a0 * w0.x; acc[0][1] += a0 * w0.y; acc[0][2] += a0 * w0.z; acc[0][3] += a0 * w0.w;
            acc[0][4] += a0 * w1.x; acc[0][5] += a0 * w1.y; acc[0][6] += a0 * w1.z; acc[0][7] += a0 * w1.w;
            acc[1][0] += a1 * w0.x; acc[1][1] += a1 * w0.y; acc[1][2] += a1 * w0.z; acc[1][3] += a1 * w0.w;
            acc[1][4] += a1 * w1.x; acc[1][5] += a1 * w1.y; acc[1][6] += a1 * w1.z; acc[1][7] += a1 * w1.w;
            acc[2][0] += a2 * w0.x; acc[2][1] += a2 * w0.y; acc[2][2] += a2 * w0.z; acc[2][3] += a2 * w0.w;
            acc[2][4] += a2 * w1.x; acc[2][5] += a2 * w1.y; acc[2][6] += a2 * w1.z; acc[2][7] += a2 * w1.w;
            acc[3][0] += a3 * w0.x; acc[3][1] += a3 * w0.y; acc[3][2] += a3 * w0.z; acc[3][3] += a3 * w0.w;
            acc[3][4] += a3 * w1.x; acc[3][5] += a3 * w1.y; acc[3][6] += a3 * w1.z; acc[3][7] += a3 * w1.w;
        }
        __syncthreads();
    }

    const float4 b0 = *reinterpret_cast<const float4*>(b + tc * 4);
    const float4 b1 = *reinterpret_cast<const float4*>(b + 64 + tc * 4);
#pragma unroll
    for (int i = 0; i < 4; i++) {
        const int rg = rowbase + tr4 + i;
        if (rg < kN) {
            float4 o0, o1;
            o0.x = fmaxf(acc[i][0] + b0.x, 0.f);
            o0.y = fmaxf(acc[i][1] + b0.y, 0.f);
            o0.z = fmaxf(acc[i][2] + b0.z, 0.f);
            o0.w = fmaxf(acc[i][3] + b0.w, 0.f);
            o1.x = fmaxf(acc[i][4] + b1.x, 0.f);
            o1.y = fmaxf(acc[i][5] + b1.y, 0.f);
            o1.z = fmaxf(acc[i][6] + b1.z, 0.f);
            o1.w = fmaxf(acc[i][7] + b1.w, 0.f);
            *reinterpret_cast<float4*>(h + (size_t)rg * kD + tc * 4) = o0;
            *reinterpret_cast<float4*>(h + (size_t)rg * kD + 64 + tc * 4) = o1;
            uint2 p0, p1;
            p0.x = f2bf_pack(o0.x, o0.y);
            p0.y = f2bf_pack(o0.z, o0.w);
            p1.x = f2bf_pack(o1.x, o1.y);
            p1.y = f2bf_pack(o1.z, o1.w);
            *reinterpret_cast<uint2*>(h16 + (size_t)rg * kD + tc * 4) = p0;
            *reinterpret_cast<uint2*>(h16 + (size_t)rg * kD + 64 + tc * 4) = p1;
        }
    }
}

// ---------------------------------------------------------------------------
// per-node attention scalars
__global__ void k_slr(const float* __restrict__ h, const float* __restrict__ attn,
                      float* __restrict__ sl, float* __restrict__ sr) {
    const int id = blockIdx.x * blockDim.x + threadIdx.x;
    if (id >= kN * kH) return;
    const int n = id >> 2;
    const int hh = id & 3;
    float4 hx[8];
    const float4* hv = reinterpret_cast<const float4*>(h + (size_t)n * kD + hh * kC);
#pragma unroll
    for (int i = 0; i < 8; i++) hx[i] = hv[i];
#pragma unroll
    for (int m = 0; m < kM; m++) {
        const float4* al = reinterpret_cast<const float4*>(attn + (m * kH + hh) * 2 * kC);
        const float4* ar = al + 8;
        float s0 = 0.f, s1 = 0.f;
#pragma unroll
        for (int i = 0; i < 8; i++) {
            const float4 a = al[i], r = ar[i], x = hx[i];
            s0 += x.x * a.x + x.y * a.y + x.z * a.z + x.w * a.w;
            s1 += x.x * r.x + x.y * r.y + x.z * r.z + x.w * r.w;
        }
        sl[((size_t)m * kN + n) * kH + hh] = s0;
        sr[((size_t)m * kN + n) * kH + hh] = s1;
    }
}

// ---------------------------------------------------------------------------
// CSR build
__global__ void k_count(const int* __restrict__ ei, int* __restrict__ cnt) {
    const int e = blockIdx.x * blockDim.x + threadIdx.x;
    if (e >= kM * kE) return;
    const int m = e / kE;
    const int el = e - m * kE;
    const int dst = ei[(size_t)m * 2 * kE + kE + el];
    atomicAdd(&cnt[m * kN + dst], 1);
}

__global__ __launch_bounds__(1024) void k_scan(const int* __restrict__ cnt,
                                               int* __restrict__ offs) {
    const int m = blockIdx.x;
    const int* c = cnt + (size_t)m * kN;
    int* o = offs + (size_t)m * (kN + 1);
    __shared__ int wsum[16];
    __shared__ int carry_s;
    const int t = threadIdx.x;
    const int w = t >> 6, l = t & 63;
    if (t == 0) carry_s = 0;
    __syncthreads();
    for (int base = 0; base < kN; base += 4096) {
        const int i0 = base + t * 4;
        const int v0 = (i0 + 0 < kN) ? c[i0 + 0] : 0;
        const int v1 = (i0 + 1 < kN) ? c[i0 + 1] : 0;
        const int v2 = (i0 + 2 < kN) ? c[i0 + 2] : 0;
        const int v3 = (i0 + 3 < kN) ? c[i0 + 3] : 0;
        const int s = v0 + v1 + v2 + v3;
        int sc = s;
#pragma unroll
        for (int d = 1; d < 64; d <<= 1) {
            const int x = __shfl_up(sc, d);
            if (l >= d) sc += x;
        }
        if (l == 63) wsum[w] = sc;
        __syncthreads();
        int woff = 0, tot = 0;
#pragma unroll
        for (int i = 0; i < 16; i++) {
            const int v = wsum[i];
            tot += v;
            if (i < w) woff += v;
        }
        const int carry = carry_s;
        __syncthreads();
        if (t == 0) carry_s = carry + tot;
        int run = carry + woff + (sc - s);
        if (i0 + 0 < kN) o[i0 + 0] = run; run += v0;
        if (i0 + 1 < kN) o[i0 + 1] = run; run += v1;
        if (i0 + 2 < kN) o[i0 + 2] = run; run += v2;
        if (i0 + 3 < kN) o[i0 + 3] = run; run += v3;
    }
    if (t == 0) o[kN] = carry_s;
}

__global__ void k_scatter(const int* __restrict__ ei, const int* __restrict__ offs,
                          int* __restrict__ cur, int* __restrict__ srcsort) {
    const int e = blockIdx.x * blockDim.x + threadIdx.x;
    if (e >= kM * kE) return;
    const int m = e / kE;
    const int el = e - m * kE;
    const int src = ei[(size_t)m * 2 * kE + el];
    const int dst = ei[(size_t)m * 2 * kE + kE + el];
    const int pos = offs[(size_t)m * (kN + 1) + dst] + atomicAdd(&cur[m * kN + dst], 1);
    srcsort[(size_t)m * kE + pos] = src;
}

// ---------------------------------------------------------------------------
// aggregation: per-dst block, wave m = metapath m. No max-shift softmax
// (shift-invariant; |logit| < ~5 so exp is safe in fp32). Cooperative
// per-(edge,head) weights via wave-local LDS broadcast; bf16 feature gather.
#define CH 16
__global__ __launch_bounds__(256) void k_agg(const unsigned short* __restrict__ h16,
                                             const float* __restrict__ h,
                                             const float* __restrict__ sl,
                                             const float* __restrict__ sr,
                                             const int* __restrict__ offs,
                                             const int* __restrict__ srcsort,
                                             const float* __restrict__ ral,
                                             const float* __restrict__ rar,
                                             const float* __restrict__ rbias,
                                             float* __restrict__ out) {
    const int dst = blockIdx.x;
    const int t = threadIdx.x;
    const int m = t >> 6;
    const int l = t & 63;
    const int hh = l >> 4;        // head for this lane
    const int jj = l & 15;        // edge slot this lane computes the weight for
    const int e0 = l * 2;         // channel pair e0, e0+1

    __shared__ float smres[kM][kD];
    __shared__ float swts[kM][64];

    const int beg = offs[(size_t)m * (kN + 1) + dst];
    const int cnt = offs[(size_t)m * (kN + 1) + dst + 1] - beg;
    const float sl_h = sl[((size_t)m * kN + dst) * kH + hh];
    const int* __restrict__ sbase = srcsort + (size_t)m * kE + beg;
    const float* __restrict__ srm = sr + (size_t)m * kN * kH;

    float sum = 0.f, a0 = 0.f, a1 = 0.f;

    for (int c = 0; c < cnt; c += CH) {
        const int nb = cnt - c;
        // broadcast loads of 16 src ids (same address across lanes -> 1 txn each;
        // over-read past cnt is safe: in-array garbage is a valid id, slack zeroed)
        int sj[CH];
#pragma unroll
        for (int j = 0; j < CH; j++) sj[j] = sbase[c + j];

        // this lane computes the weight for (edge jj, head hh)
        float x = sl_h + srm[(size_t)sj[jj] * kH + hh];
        x = x > 0.f ? x : 0.2f * x;           // LeakyReLU(0.2)
        float w = (jj < nb) ? __expf(x) : 0.f;
        sum += w;
        swts[m][l] = w;
        __builtin_amdgcn_wave_barrier();      // wave-local LDS broadcast (in-order DS pipe)
        const float4 w0 = *reinterpret_cast<const float4*>(&swts[m][hh * 16]);
        const float4 w1 = *reinterpret_cast<const float4*>(&swts[m][hh * 16 + 4]);
        const float4 w2 = *reinterpret_cast<const float4*>(&swts[m][hh * 16 + 8]);
        const float4 w3 = *reinterpret_cast<const float4*>(&swts[m][hh * 16 + 12]);
        __builtin_amdgcn_wave_barrier();
        const float wj[CH] = {w0.x, w0.y, w0.z, w0.w, w1.x, w1.y, w1.z, w1.w,
                              w2.x, w2.y, w2.z, w2.w, w3.x, w3.y, w3.z, w3.w};
#pragma unroll
        for (int j = 0; j < CH; j++) {
            if (wj[j] != 0.f) {               // uniform-false for tail slots -> execz skip
                const unsigned int u =
                    *reinterpret_cast<const unsigned int*>(h16 + (size_t)sj[j] * kD + e0);
                const float f0 = __uint_as_float(u << 16);
                const float f1 = __uint_as_float(u & 0xffff0000u);
                a0 += wj[j] * f0;
                a1 += wj[j] * f1;
            }
        }
    }
    // head-group (16-lane) sum reduction
    sum += __shfl_xor(sum, 1);
    sum += __shfl_xor(sum, 2);
    sum += __shfl_xor(sum, 4);
    sum += __shfl_xor(sum, 8);
    const float inv = 1.0f / (sum + 1e-16f);
    smres[m][e0] = a0 * inv;
    smres[m][e0 + 1] = a1 * inv;
    __syncthreads();

    if (m == 0) {
        const float2 hd = *reinterpret_cast<const float2*>(h + (size_t)dst * kD + e0);
        const float bl0 = fmaxf(hd.x * ral[e0], 0.f);
        const float bl1 = fmaxf(hd.y * ral[e0 + 1], 0.f);
        float emb0[5], emb1[5], beta[5];
#pragma unroll
        for (int r = 0; r < 5; r++) {
            const float x0 = (r < 4) ? smres[r][e0] : hd.x;
            const float x1 = (r < 4) ? smres[r][e0 + 1] : hd.y;
            emb0[r] = x0;
            emb1[r] = x1;
            const float br0 = fmaxf(x0 * rar[r * kD + e0], 0.f);
            const float br1 = fmaxf(x1 * rar[r * kD + e0 + 1], 0.f);
            float p = bl0 * br0 + bl1 * br1;
            p += __shfl_xor(p, 1);
            p += __shfl_xor(p, 2);
            p += __shfl_xor(p, 4);
            p += __shfl_xor(p, 8);
            beta[r] = p + rbias[r];
        }
        float mx = beta[0];
#pragma unroll
        for (int r = 1; r < 5; r++) mx = fmaxf(mx, beta[r]);
        float s = 0.f, wgt[5];
#pragma unroll
        for (int r = 0; r < 5; r++) { wgt[r] = __expf(beta[r] - mx); s += wgt[r]; }
        const float invb = 1.f / s;
        float o0 = 0.f, o1 = 0.f;
#pragma unroll
        for (int r = 0; r < 5; r++) { o0 += emb0[r] * wgt[r]; o1 += emb1[r] * wgt[r]; }
        out[(size_t)dst * kD + e0] = fmaxf(o0 * invb, 0.f);
        out[(size_t)dst * kD + e0 + 1] = fmaxf(o1 * invb, 0.f);
    }
}

// ---------------------------------------------------------------------------
extern "C" void kernel_launch(void* const* d_in, const int* in_sizes, int n_in,
                              void* d_out, int out_size, void* d_ws, size_t ws_size,
                              hipStream_t stream) {
    const float* feats = (const float*)d_in[0];
    const int* ei      = (const int*)d_in[1];
    const float* W     = (const float*)d_in[2];
    const float* b     = (const float*)d_in[3];
    const float* attn  = (const float*)d_in[4];
    const float* ral   = (const float*)d_in[5];
    const float* rar   = (const float*)d_in[6];
    const float* rbias = (const float*)d_in[7];
    float* out = (float*)d_out;

    char* ws = (char*)d_ws;
    size_t off = 0;
    auto alloc = [&](size_t bytes) -> void* {
        void* p = ws + off;
        off = (off + bytes + 255) & ~(size_t)255;
        return p;
    };
    float* h    = (float*)alloc(sizeof(float) * (size_t)kN * kD);              // 25.6 MB
    unsigned short* h16 = (unsigned short*)alloc(sizeof(short) * (size_t)kN * kD); // 12.8 MB
    float* sl   = (float*)alloc(sizeof(float) * (size_t)kM * kN * kH);         // 3.2 MB
    float* sr   = (float*)alloc(sizeof(float) * (size_t)kM * kN * kH);         // 3.2 MB
    int* cnt    = (int*)alloc(sizeof(int) * (size_t)2 * kM * kN);              // cnt+cur
    int* cur    = cnt + (size_t)kM * kN;
    int* offs   = (int*)alloc(sizeof(int) * (size_t)kM * (kN + 1));
    int* srcsort= (int*)alloc(sizeof(int) * ((size_t)kM * kE + 64));           // + zeroed slack

    k_zero<<<(2 * kM * kN + 255) / 256, 256, 0, stream>>>(cnt, 2 * kM * kN);
    k_zero<<<1, 64, 0, stream>>>(srcsort + (size_t)kM * kE, 64);
    k_gemm<<<(kN + 63) / 64, 256, 0, stream>>>(feats, W, b, h, h16);
    k_slr<<<(kN * kH + 255) / 256, 256, 0, stream>>>(h, attn, sl, sr);
    k_count<<<(kM * kE + 255) / 256, 256, 0, stream>>>(ei, cnt);
    k_scan<<<kM, 1024, 0, stream>>>(cnt, offs);
    k_scatter<<<(kM * kE + 255) / 256, 256, 0, stream>>>(ei, offs, cur, srcsort);
    k_agg<<<kN, 256, 0, stream>>>(h16, h, sl, sr, offs, srcsort, ral, rar, rbias, out);
}

// Round 4
// 691.093 us; speedup vs baseline: 1.1171x; 1.1171x over previous
//
#include <hip/hip_runtime.h>
#include <math.h>

// Problem constants
#define kN 50000
#define kE 800000
#define kM 4
#define kH 4
#define kC 32
#define kIN 256
#define kD 128   // kH*kC

__device__ __forceinline__ unsigned int f2bf_pack(float a, float b) {
    unsigned ua = __float_as_uint(a);
    ua += 0x7fffu + ((ua >> 16) & 1u);          // RNE
    unsigned ub = __float_as_uint(b);
    ub += 0x7fffu + ((ub >> 16) & 1u);
    return (ua >> 16) | (ub & 0xffff0000u);
}

// ---------------------------------------------------------------------------
// h[n][128] = relu(feats[n][256] @ W[256][128] + b); also emit bf16 copy h16
__global__ __launch_bounds__(256) void k_gemm(const float* __restrict__ feats,
                                              const float* __restrict__ W,
                                              const float* __restrict__ b,
                                              float* __restrict__ h,
                                              unsigned short* __restrict__ h16) {
    __shared__ float fr[64][68];    // [row][k], pad to break bank conflicts
    __shared__ float wc[64][128];   // [k][col]
    const int t = threadIdx.x;
    const int rowbase = blockIdx.x * 64;
    const int tr4 = (t >> 4) * 4;   // rows tr4..tr4+3
    const int tc = t & 15;          // cols tc*4..+3 and 64+tc*4..+3

    float acc[4][8];
#pragma unroll
    for (int i = 0; i < 4; i++)
#pragma unroll
        for (int j = 0; j < 8; j++) acc[i][j] = 0.f;

    for (int kc = 0; kc < kIN; kc += 64) {
        {
            const int row = t >> 4;   // 0..15
            const int k4 = t & 15;    // 0..15
#pragma unroll
            for (int i = 0; i < 4; i++) {
                const int r = row + i * 16;
                const int rg = rowbase + r;
                float4 v = make_float4(0.f, 0.f, 0.f, 0.f);
                if (rg < kN)
                    v = *reinterpret_cast<const float4*>(feats + rg * kIN + kc + k4 * 4);
                *reinterpret_cast<float4*>(&fr[r][k4 * 4]) = v;
            }
        }
#pragma unroll
        for (int i = 0; i < 8; i++) {
            const int v4 = t + i * 256;
            const int kk = v4 >> 5;
            const int c4 = v4 & 31;
            *reinterpret_cast<float4*>(&wc[kk][c4 * 4]) =
                *reinterpret_cast<const float4*>(W + (size_t)(kc + kk) * kD + c4 * 4);
        }
        __syncthreads();

#pragma unroll 8
        for (int k = 0; k < 64; k++) {
            const float a0 = fr[tr4 + 0][k];
            const float a1 = fr[tr4 + 1][k];
            const float a2 = fr[tr4 + 2][k];
            const float a3 = fr[tr4 + 3][k];
            const float4 w0 = *reinterpret_cast<const float4*>(&wc[k][tc * 4]);
            const float4 w1 = *reinterpret_cast<const float4*>(&wc[k][64 + tc * 4]);
            acc[0][0] += a0 * w0.x; acc[0][1] += a0 * w0.y; acc[0][2] += a0 * w0.z; acc[0][3] += a0 * w0.w;
            acc[0][4] += a0 * w1.x; acc[0][5] += a0 * w1.y; acc[0][6] += a0 * w1.z; acc[0][7] += a0 * w1.w;
            acc[1][0] += a1 * w0.x; acc[1][1] += a1 * w0.y; acc[1][2] += a1 * w0.z; acc[1][3] += a1 * w0.w;
            acc[1][4] += a1 * w1.x; acc[1][5] += a1 * w1.y; acc[1][6] += a1 * w1.z; acc[1][7] += a1 * w1.w;
            acc[2][0] += a2 * w0.x; acc[2][1] += a2 * w0.y; acc[2][2] += a2 * w0.z; acc[2][3] += a2 * w0.w;
            acc[2][4] += a2 * w1.x; acc[2][5] += a2 * w1.y; acc[2][6] += a2 * w1.z; acc[2][7] += a2 * w1.w;
            acc[3][0] += a3 * w0.x; acc[3][1] += a3 * w0.y; acc[3][2] += a3 * w0.z; acc[3][3] += a3 * w0.w;
            acc[3][4] += a3 * w1.x; acc[3][5] += a3 * w1.y; acc[3][6] += a3 * w1.z; acc[3][7] += a3 * w1.w;
        }
        __syncthreads();
    }

    const float4 b0 = *reinterpret_cast<const float4*>(b + tc * 4);
    const float4 b1 = *reinterpret_cast<const float4*>(b + 64 + tc * 4);
#pragma unroll
    for (int i = 0; i < 4; i++) {
        const int rg = rowbase + tr4 + i;
        if (rg < kN) {
            float4 o0, o1;
            o0.x = fmaxf(acc[i][0] + b0.x, 0.f);
            o0.y = fmaxf(acc[i][1] + b0.y, 0.f);
            o0.z = fmaxf(acc[i][2] + b0.z, 0.f);
            o0.w = fmaxf(acc[i][3] + b0.w, 0.f);
            o1.x = fmaxf(acc[i][4] + b1.x, 0.f);
            o1.y = fmaxf(acc[i][5] + b1.y, 0.f);
            o1.z = fmaxf(acc[i][6] + b1.z, 0.f);
            o1.w = fmaxf(acc[i][7] + b1.w, 0.f);
            *reinterpret_cast<float4*>(h + (size_t)rg * kD + tc * 4) = o0;
            *reinterpret_cast<float4*>(h + (size_t)rg * kD + 64 + tc * 4) = o1;
            uint2 p0, p1;
            p0.x = f2bf_pack(o0.x, o0.y);
            p0.y = f2bf_pack(o0.z, o0.w);
            p1.x = f2bf_pack(o1.x, o1.y);
            p1.y = f2bf_pack(o1.z, o1.w);
            *reinterpret_cast<uint2*>(h16 + (size_t)rg * kD + tc * 4) = p0;
            *reinterpret_cast<uint2*>(h16 + (size_t)rg * kD + 64 + tc * 4) = p1;
        }
    }
}

// ---------------------------------------------------------------------------
// per-node attention scalars
__global__ void k_slr(const float* __restrict__ h, const float* __restrict__ attn,
                      float* __restrict__ sl, float* __restrict__ sr) {
    const int id = blockIdx.x * blockDim.x + threadIdx.x;
    if (id >= kN * kH) return;
    const int n = id >> 2;
    const int hh = id & 3;
    float4 hx[8];
    const float4* hv = reinterpret_cast<const float4*>(h + (size_t)n * kD + hh * kC);
#pragma unroll
    for (int i = 0; i < 8; i++) hx[i] = hv[i];
#pragma unroll
    for (int m = 0; m < kM; m++) {
        const float4* al = reinterpret_cast<const float4*>(attn + (m * kH + hh) * 2 * kC);
        const float4* ar = al + 8;
        float s0 = 0.f, s1 = 0.f;
#pragma unroll
        for (int i = 0; i < 8; i++) {
            const float4 a = al[i], r = ar[i], x = hx[i];
            s0 += x.x * a.x + x.y * a.y + x.z * a.z + x.w * a.w;
            s1 += x.x * r.x + x.y * r.y + x.z * r.z + x.w * r.w;
        }
        sl[((size_t)m * kN + n) * kH + hh] = s0;
        sr[((size_t)m * kN + n) * kH + hh] = s1;
    }
}

// ---------------------------------------------------------------------------
// CSR build: degree count, 4 edges per thread via int4
__global__ void k_count(const int* __restrict__ ei, int* __restrict__ cnt) {
    const int i = blockIdx.x * blockDim.x + threadIdx.x;
    if (i >= kM * kE / 4) return;
    const int m = i / (kE / 4);
    const int el4 = i - m * (kE / 4);
    const int4 d = *reinterpret_cast<const int4*>(ei + (size_t)m * 2 * kE + kE + el4 * 4);
    atomicAdd(&cnt[m * kN + d.x], 1);
    atomicAdd(&cnt[m * kN + d.y], 1);
    atomicAdd(&cnt[m * kN + d.z], 1);
    atomicAdd(&cnt[m * kN + d.w], 1);
}

__global__ __launch_bounds__(1024) void k_scan(const int* __restrict__ cnt,
                                               int* __restrict__ offs) {
    const int m = blockIdx.x;
    const int* c = cnt + (size_t)m * kN;
    int* o = offs + (size_t)m * (kN + 1);
    __shared__ int wsum[16];
    __shared__ int carry_s;
    const int t = threadIdx.x;
    const int w = t >> 6, l = t & 63;
    if (t == 0) carry_s = 0;
    __syncthreads();
    for (int base = 0; base < kN; base += 4096) {
        const int i0 = base + t * 4;
        const int v0 = (i0 + 0 < kN) ? c[i0 + 0] : 0;
        const int v1 = (i0 + 1 < kN) ? c[i0 + 1] : 0;
        const int v2 = (i0 + 2 < kN) ? c[i0 + 2] : 0;
        const int v3 = (i0 + 3 < kN) ? c[i0 + 3] : 0;
        const int s = v0 + v1 + v2 + v3;
        int sc = s;
#pragma unroll
        for (int d = 1; d < 64; d <<= 1) {
            const int x = __shfl_up(sc, d);
            if (l >= d) sc += x;
        }
        if (l == 63) wsum[w] = sc;
        __syncthreads();
        int woff = 0, tot = 0;
#pragma unroll
        for (int i = 0; i < 16; i++) {
            const int v = wsum[i];
            tot += v;
            if (i < w) woff += v;
        }
        const int carry = carry_s;
        __syncthreads();
        if (t == 0) carry_s = carry + tot;
        int run = carry + woff + (sc - s);
        if (i0 + 0 < kN) o[i0 + 0] = run; run += v0;
        if (i0 + 1 < kN) o[i0 + 1] = run; run += v1;
        if (i0 + 2 < kN) o[i0 + 2] = run; run += v2;
        if (i0 + 3 < kN) o[i0 + 3] = run; run += v3;
    }
    if (t == 0) o[kN] = carry_s;
}

__global__ void k_scatter(const int* __restrict__ ei, const int* __restrict__ offs,
                          int* __restrict__ cur, int* __restrict__ srcsort) {
    const int e = blockIdx.x * blockDim.x + threadIdx.x;
    if (e >= kM * kE) return;
    const int m = e / kE;
    const int el = e - m * kE;
    const int src = ei[(size_t)m * 2 * kE + el];
    const int dst = ei[(size_t)m * 2 * kE + kE + el];
    const int pos = offs[(size_t)m * (kN + 1) + dst] + atomicAdd(&cur[m * kN + dst], 1);
    srcsort[(size_t)m * kE + pos] = src;
}

// ---------------------------------------------------------------------------
// aggregation: per-dst block, wave m = metapath m. No max-shift softmax
// (shift-invariant, |logit| small). Cooperative per-(edge,head) weights via
// wave-local LDS broadcast. Full chunks are branch-free so all 16 bf16
// gathers stay in flight (MLP); tail chunk clamps invalid slots to dst
// (cache-hot line, weight 0) instead of branching around loads.
#define CH 16
__global__ __launch_bounds__(256) void k_agg(const unsigned short* __restrict__ h16,
                                             const float* __restrict__ h,
                                             const float* __restrict__ sl,
                                             const float* __restrict__ sr,
                                             const int* __restrict__ offs,
                                             const int* __restrict__ srcsort,
                                             const float* __restrict__ ral,
                                             const float* __restrict__ rar,
                                             const float* __restrict__ rbias,
                                             float* __restrict__ out) {
    const int dst = blockIdx.x;
    const int t = threadIdx.x;
    const int m = t >> 6;
    const int l = t & 63;
    const int hh = l >> 4;        // head for this lane
    const int jj = l & 15;        // edge slot this lane computes the weight for
    const int e0 = l * 2;         // channel pair e0, e0+1

    __shared__ float smres[kM][kD];
    __shared__ float swts[kM][64];
    __shared__ int sids[kM][64];

    const int beg = offs[(size_t)m * (kN + 1) + dst];
    const int cnt = offs[(size_t)m * (kN + 1) + dst + 1] - beg;
    const float sl_h = sl[((size_t)m * kN + dst) * kH + hh];
    const int* __restrict__ sbase = srcsort + (size_t)m * kE + beg;
    const float* __restrict__ srm = sr + (size_t)m * kN * kH;

    float sum = 0.f, a0 = 0.f, a1 = 0.f;
    const int cfull = cnt & ~(CH - 1);

    // ---- full chunks: branch-free, 16 gathers in flight ----
    for (int c = 0; c < cfull; c += CH) {
        const int my = sbase[c + jj];          // 16 distinct addrs, 4x broadcast
        sids[m][l] = my;
        const float srv = srm[(size_t)my * kH + hh];
        __builtin_amdgcn_wave_barrier();
        int sj[CH];
        *reinterpret_cast<int4*>(&sj[0])  = *reinterpret_cast<const int4*>(&sids[m][0]);
        *reinterpret_cast<int4*>(&sj[4])  = *reinterpret_cast<const int4*>(&sids[m][4]);
        *reinterpret_cast<int4*>(&sj[8])  = *reinterpret_cast<const int4*>(&sids[m][8]);
        *reinterpret_cast<int4*>(&sj[12]) = *reinterpret_cast<const int4*>(&sids[m][12]);
        float x = sl_h + srv;
        x = x > 0.f ? x : 0.2f * x;            // LeakyReLU(0.2)
        const float w = __expf(x);
        sum += w;
        swts[m][l] = w;
        __builtin_amdgcn_wave_barrier();
        const float4 w0 = *reinterpret_cast<const float4*>(&swts[m][hh * 16]);
        const float4 w1 = *reinterpret_cast<const float4*>(&swts[m][hh * 16 + 4]);
        const float4 w2 = *reinterpret_cast<const float4*>(&swts[m][hh * 16 + 8]);
        const float4 w3 = *reinterpret_cast<const float4*>(&swts[m][hh * 16 + 12]);
        __builtin_amdgcn_wave_barrier();
        unsigned int u[CH];
#pragma unroll
        for (int j = 0; j < CH; j++)
            u[j] = *reinterpret_cast<const unsigned int*>(h16 + (size_t)sj[j] * kD + e0);
        const float wj[CH] = {w0.x, w0.y, w0.z, w0.w, w1.x, w1.y, w1.z, w1.w,
                              w2.x, w2.y, w2.z, w2.w, w3.x, w3.y, w3.z, w3.w};
#pragma unroll
        for (int j = 0; j < CH; j++) {
            a0 += wj[j] * __uint_as_float(u[j] << 16);
            a1 += wj[j] * __uint_as_float(u[j] & 0xffff0000u);
        }
    }

    // ---- tail chunk: invalid slots clamped to dst (hot line), weight 0 ----
    if (cfull < cnt) {
        const int c = cfull;
        const int my = sbase[c + jj];          // over-read lands in next segment / zeroed slack
        sids[m][l] = my;
        const float srv = srm[(size_t)my * kH + hh];
        __builtin_amdgcn_wave_barrier();
        int sj[CH];
        *reinterpret_cast<int4*>(&sj[0])  = *reinterpret_cast<const int4*>(&sids[m][0]);
        *reinterpret_cast<int4*>(&sj[4])  = *reinterpret_cast<const int4*>(&sids[m][4]);
        *reinterpret_cast<int4*>(&sj[8])  = *reinterpret_cast<const int4*>(&sids[m][8]);
        *reinterpret_cast<int4*>(&sj[12]) = *reinterpret_cast<const int4*>(&sids[m][12]);
        float x = sl_h + srv;
        x = x > 0.f ? x : 0.2f * x;
        const float w = (c + jj < cnt) ? __expf(x) : 0.f;
        sum += w;
        swts[m][l] = w;
        __builtin_amdgcn_wave_barrier();
        const float4 w0 = *reinterpret_cast<const float4*>(&swts[m][hh * 16]);
        const float4 w1 = *reinterpret_cast<const float4*>(&swts[m][hh * 16 + 4]);
        const float4 w2 = *reinterpret_cast<const float4*>(&swts[m][hh * 16 + 8]);
        const float4 w3 = *reinterpret_cast<const float4*>(&swts[m][hh * 16 + 12]);
        __builtin_amdgcn_wave_barrier();
        const int nb = cnt - c;
#pragma unroll
        for (int j = 0; j < CH; j++) sj[j] = (j < nb) ? sj[j] : dst;
        unsigned int u[CH];
#pragma unroll
        for (int j = 0; j < CH; j++)
            u[j] = *reinterpret_cast<const unsigned int*>(h16 + (size_t)sj[j] * kD + e0);
        const float wj[CH] = {w0.x, w0.y, w0.z, w0.w, w1.x, w1.y, w1.z, w1.w,
                              w2.x, w2.y, w2.z, w2.w, w3.x, w3.y, w3.z, w3.w};
#pragma unroll
        for (int j = 0; j < CH; j++) {
            a0 += wj[j] * __uint_as_float(u[j] << 16);
            a1 += wj[j] * __uint_as_float(u[j] & 0xffff0000u);
        }
    }

    // head-group (16-lane) sum reduction
    sum += __shfl_xor(sum, 1);
    sum += __shfl_xor(sum, 2);
    sum += __shfl_xor(sum, 4);
    sum += __shfl_xor(sum, 8);
    const float inv = 1.0f / (sum + 1e-16f);
    smres[m][e0] = a0 * inv;
    smres[m][e0 + 1] = a1 * inv;
    __syncthreads();

    if (m == 0) {
        const float2 hd = *reinterpret_cast<const float2*>(h + (size_t)dst * kD + e0);
        const float bl0 = fmaxf(hd.x * ral[e0], 0.f);
        const float bl1 = fmaxf(hd.y * ral[e0 + 1], 0.f);
        float emb0[5], emb1[5], beta[5];
#pragma unroll
        for (int r = 0; r < 5; r++) {
            const float x0 = (r < 4) ? smres[r][e0] : hd.x;
            const float x1 = (r < 4) ? smres[r][e0 + 1] : hd.y;
            emb0[r] = x0;
            emb1[r] = x1;
            const float br0 = fmaxf(x0 * rar[r * kD + e0], 0.f);
            const float br1 = fmaxf(x1 * rar[r * kD + e0 + 1], 0.f);
            float p = bl0 * br0 + bl1 * br1;
            p += __shfl_xor(p, 1);
            p += __shfl_xor(p, 2);
            p += __shfl_xor(p, 4);
            p += __shfl_xor(p, 8);
            beta[r] = p + rbias[r];
        }
        float mx = beta[0];
#pragma unroll
        for (int r = 1; r < 5; r++) mx = fmaxf(mx, beta[r]);
        float s = 0.f, wgt[5];
#pragma unroll
        for (int r = 0; r < 5; r++) { wgt[r] = __expf(beta[r] - mx); s += wgt[r]; }
        const float invb = 1.f / s;
        float o0 = 0.f, o1 = 0.f;
#pragma unroll
        for (int r = 0; r < 5; r++) { o0 += emb0[r] * wgt[r]; o1 += emb1[r] * wgt[r]; }
        out[(size_t)dst * kD + e0] = fmaxf(o0 * invb, 0.f);
        out[(size_t)dst * kD + e0 + 1] = fmaxf(o1 * invb, 0.f);
    }
}

// ---------------------------------------------------------------------------
extern "C" void kernel_launch(void* const* d_in, const int* in_sizes, int n_in,
                              void* d_out, int out_size, void* d_ws, size_t ws_size,
                              hipStream_t stream) {
    const float* feats = (const float*)d_in[0];
    const int* ei      = (const int*)d_in[1];
    const float* W     = (const float*)d_in[2];
    const float* b     = (const float*)d_in[3];
    const float* attn  = (const float*)d_in[4];
    const float* ral   = (const float*)d_in[5];
    const float* rar   = (const float*)d_in[6];
    const float* rbias = (const float*)d_in[7];
    float* out = (float*)d_out;

    char* ws = (char*)d_ws;
    size_t off = 0;
    auto alloc = [&](size_t bytes) -> void* {
        void* p = ws + off;
        off = (off + bytes + 255) & ~(size_t)255;
        return p;
    };
    float* h    = (float*)alloc(sizeof(float) * (size_t)kN * kD);              // 25.6 MB
    unsigned short* h16 = (unsigned short*)alloc(sizeof(short) * (size_t)kN * kD); // 12.8 MB
    float* sl   = (float*)alloc(sizeof(float) * (size_t)kM * kN * kH);         // 3.2 MB
    float* sr   = (float*)alloc(sizeof(float) * (size_t)kM * kN * kH);         // 3.2 MB
    int* cnt    = (int*)alloc(sizeof(int) * (size_t)2 * kM * kN);              // cnt+cur
    int* cur    = cnt + (size_t)kM * kN;
    int* offs   = (int*)alloc(sizeof(int) * (size_t)kM * (kN + 1));
    int* srcsort= (int*)alloc(sizeof(int) * ((size_t)kM * kE + 64));           // + zeroed slack

    hipMemsetAsync(cnt, 0, sizeof(int) * (size_t)2 * kM * kN, stream);
    hipMemsetAsync(srcsort + (size_t)kM * kE, 0, sizeof(int) * 64, stream);
    k_gemm<<<(kN + 63) / 64, 256, 0, stream>>>(feats, W, b, h, h16);
    k_slr<<<(kN * kH + 255) / 256, 256, 0, stream>>>(h, attn, sl, sr);
    k_count<<<(kM * kE / 4 + 255) / 256, 256, 0, stream>>>(ei, cnt);
    k_scan<<<kM, 1024, 0, stream>>>(cnt, offs);
    k_scatter<<<(kM * kE + 255) / 256, 256, 0, stream>>>(ei, offs, cur, srcsort);
    k_agg<<<kN, 256, 0, stream>>>(h16, h, sl, sr, offs, srcsort, ral, rar, rbias, out);
}

// Round 5
// 637.276 us; speedup vs baseline: 1.2114x; 1.0844x over previous
//
#include <hip/hip_runtime.h>
#include <math.h>

// Problem constants
#define kN 50000
#define kE 800000
#define kM 4
#define kH 4
#define kC 32
#define kIN 256
#define kD 128   // kH*kC

typedef __attribute__((ext_vector_type(8))) short bf16x8;
typedef __attribute__((ext_vector_type(4))) float f32x4;

__device__ __forceinline__ unsigned int f2bf_pack(float a, float b) {
    unsigned ua = __float_as_uint(a);
    ua += 0x7fffu + ((ua >> 16) & 1u);          // RNE
    unsigned ub = __float_as_uint(b);
    ub += 0x7fffu + ((ub >> 16) & 1u);
    return (ua >> 16) | (ub & 0xffff0000u);
}
__device__ __forceinline__ unsigned short f2bf(float x) {
    unsigned u = __float_as_uint(x);
    u += 0x7fffu + ((u >> 16) & 1u);
    return (unsigned short)(u >> 16);
}

// ---------------------------------------------------------------------------
// Wt16[col][k] = bf16(W[k][col])  (128 cols x 256 k)
__global__ void k_wcast(const float* __restrict__ W, unsigned short* __restrict__ Wt16) {
    const int col = blockIdx.x;        // 0..127
    const int k = threadIdx.x;         // 0..255
    Wt16[(size_t)col * kIN + k] = f2bf(W[(size_t)k * kD + col]);
}

// ---------------------------------------------------------------------------
// MFMA bf16 GEMM: h16[n][128] = bf16(relu(feats[n][256] @ W + b))
// 128-row tile per block, 4 waves: wave covers 64x64 quadrant (4x4 MFMA grid,
// 16x16x32). A staged to LDS as bf16 [row][32k]; B fragments loaded directly
// from Wt16 (L2-resident, 64 KB). fp32 accumulation.
__global__ __launch_bounds__(256) void k_gemm(const float* __restrict__ feats,
                                              const unsigned short* __restrict__ Wt16,
                                              const float* __restrict__ b,
                                              unsigned short* __restrict__ h16) {
    __shared__ unsigned short fr16[128 * 32];   // 8 KB: A chunk [row][32k]
    const int t = threadIdx.x;
    const int lane = t & 63;
    const int wave = t >> 6;
    const int q = lane >> 4;           // quad 0..3
    const int m16 = lane & 15;
    const int wrow = (wave >> 1) * 64;
    const int wcol = (wave & 1) * 64;
    const int rowbase = blockIdx.x * 128;

    f32x4 acc[4][4];
#pragma unroll
    for (int i = 0; i < 4; i++)
#pragma unroll
        for (int j = 0; j < 4; j++) acc[i][j] = (f32x4){0.f, 0.f, 0.f, 0.f};

    const int srow = t >> 3;           // staging: 32 rows per pass
    const int sk4 = t & 7;             // float4 slot along k (8 slots = 32 k)

    for (int kc = 0; kc < kIN; kc += 32) {
        __syncthreads();
#pragma unroll
        for (int it = 0; it < 4; it++) {
            const int row = srow + it * 32;
            const int rg = rowbase + row;
            float4 v = make_float4(0.f, 0.f, 0.f, 0.f);
            if (rg < kN)
                v = *reinterpret_cast<const float4*>(feats + (size_t)rg * kIN + kc + sk4 * 4);
            uint2 p;
            p.x = f2bf_pack(v.x, v.y);
            p.y = f2bf_pack(v.z, v.w);
            *reinterpret_cast<uint2*>(&fr16[row * 32 + sk4 * 4]) = p;
        }
        __syncthreads();

        bf16x8 afr[4], bfr[4];
#pragma unroll
        for (int ri = 0; ri < 4; ri++)
            afr[ri] = *reinterpret_cast<const bf16x8*>(
                &fr16[(wrow + ri * 16 + m16) * 32 + q * 8]);
#pragma unroll
        for (int ci = 0; ci < 4; ci++)
            bfr[ci] = *reinterpret_cast<const bf16x8*>(
                Wt16 + (size_t)(wcol + ci * 16 + m16) * kIN + kc + q * 8);
#pragma unroll
        for (int ri = 0; ri < 4; ri++)
#pragma unroll
            for (int ci = 0; ci < 4; ci++)
                acc[ri][ci] = __builtin_amdgcn_mfma_f32_16x16x32_bf16(
                    afr[ri], bfr[ci], acc[ri][ci], 0, 0, 0);
    }

    float bcol[4];
#pragma unroll
    for (int ci = 0; ci < 4; ci++) bcol[ci] = b[wcol + ci * 16 + m16];

#pragma unroll
    for (int ri = 0; ri < 4; ri++) {
#pragma unroll
        for (int reg = 0; reg < 4; reg++) {
            const int row = rowbase + wrow + ri * 16 + q * 4 + reg;
            if (row < kN) {
#pragma unroll
                for (int ci = 0; ci < 4; ci++) {
                    const int col = wcol + ci * 16 + m16;
                    const float v = fmaxf(acc[ri][ci][reg] + bcol[ci], 0.f);
                    h16[(size_t)row * kD + col] = f2bf(v);
                }
            }
        }
    }
}

// ---------------------------------------------------------------------------
// per-node attention scalars from h16
__global__ void k_slr(const unsigned short* __restrict__ h16,
                      const float* __restrict__ attn,
                      float* __restrict__ sl, float* __restrict__ sr) {
    const int id = blockIdx.x * blockDim.x + threadIdx.x;
    if (id >= kN * kH) return;
    const int n = id >> 2;
    const int hh = id & 3;
    const unsigned int* hu =
        reinterpret_cast<const unsigned int*>(h16 + (size_t)n * kD + hh * kC);
    unsigned int u[16];
    uint4 u4;
#pragma unroll
    for (int i = 0; i < 4; i++) {
        u4 = reinterpret_cast<const uint4*>(hu)[i];
        u[i * 4 + 0] = u4.x; u[i * 4 + 1] = u4.y; u[i * 4 + 2] = u4.z; u[i * 4 + 3] = u4.w;
    }
    float f0[16], f1[16];
#pragma unroll
    for (int c = 0; c < 16; c++) {
        f0[c] = __uint_as_float(u[c] << 16);
        f1[c] = __uint_as_float(u[c] & 0xffff0000u);
    }
#pragma unroll
    for (int m = 0; m < kM; m++) {
        const float2* al = reinterpret_cast<const float2*>(attn + (m * kH + hh) * 2 * kC);
        const float2* ar = al + 16;
        float s0 = 0.f, s1 = 0.f;
#pragma unroll
        for (int c = 0; c < 16; c++) {
            const float2 a = al[c], r = ar[c];
            s0 += f0[c] * a.x + f1[c] * a.y;
            s1 += f0[c] * r.x + f1[c] * r.y;
        }
        sl[((size_t)m * kN + n) * kH + hh] = s0;
        sr[((size_t)m * kN + n) * kH + hh] = s1;
    }
}

// ---------------------------------------------------------------------------
// CSR build: degree count, 4 edges per thread via int4
__global__ void k_count(const int* __restrict__ ei, int* __restrict__ cnt) {
    const int i = blockIdx.x * blockDim.x + threadIdx.x;
    if (i >= kM * kE / 4) return;
    const int m = i / (kE / 4);
    const int el4 = i - m * (kE / 4);
    const int4 d = *reinterpret_cast<const int4*>(ei + (size_t)m * 2 * kE + kE + el4 * 4);
    atomicAdd(&cnt[m * kN + d.x], 1);
    atomicAdd(&cnt[m * kN + d.y], 1);
    atomicAdd(&cnt[m * kN + d.z], 1);
    atomicAdd(&cnt[m * kN + d.w], 1);
}

// ---------------------------------------------------------------------------
// 3-phase parallel exclusive scan over the flat 200000-counter array.
// Per-m totals are exactly kE, so one global scan serves all metapaths:
// offs[m][i] = globalscan(m*kN+i) - m*kE.
#define SCB 2048
#define SCBLOCKS ((kM * kN + SCB - 1) / SCB)   // 98

__global__ __launch_bounds__(256) void k_bsum(const int* __restrict__ cnt,
                                              int* __restrict__ bsum) {
    const int base = blockIdx.x * SCB;
    const int t = threadIdx.x;
    int s = 0;
#pragma unroll
    for (int i = 0; i < 8; i++) {
        const int g = base + t * 8 + i;
        if (g < kM * kN) s += cnt[g];
    }
#pragma unroll
    for (int d = 1; d < 64; d <<= 1) s += __shfl_xor(s, d);
    __shared__ int ws[4];
    if ((t & 63) == 0) ws[t >> 6] = s;
    __syncthreads();
    if (t == 0) bsum[blockIdx.x] = ws[0] + ws[1] + ws[2] + ws[3];
}

__global__ __launch_bounds__(128) void k_bscan(const int* __restrict__ bsum,
                                               int* __restrict__ bpre,
                                               int* __restrict__ offs) {
    const int t = threadIdx.x;
    const int lane = t & 63, wid = t >> 6;
    int v = (t < SCBLOCKS) ? bsum[t] : 0;
    int incl = v;
#pragma unroll
    for (int d = 1; d < 64; d <<= 1) {
        const int x = __shfl_up(incl, d);
        if (lane >= d) incl += x;
    }
    __shared__ int wt[2];
    if (lane == 63) wt[wid] = incl;
    __syncthreads();
    const int add = (wid == 1) ? wt[0] : 0;
    if (t < SCBLOCKS) bpre[t] = incl - v + add;
    if (t < kM) offs[t * (kN + 1) + kN] = kE;   // per-m sentinel
}

__global__ __launch_bounds__(256) void k_scanout(const int* __restrict__ cnt,
                                                 const int* __restrict__ bpre,
                                                 int* __restrict__ offs) {
    const int base = blockIdx.x * SCB;
    const int t = threadIdx.x;
    const int lane = t & 63, wid = t >> 6;
    int v[8];
    int s = 0;
#pragma unroll
    for (int i = 0; i < 8; i++) {
        const int g = base + t * 8 + i;
        v[i] = (g < kM * kN) ? cnt[g] : 0;
        s += v[i];
    }
    int incl = s;
#pragma unroll
    for (int d = 1; d < 64; d <<= 1) {
        const int x = __shfl_up(incl, d);
        if (lane >= d) incl += x;
    }
    __shared__ int wt[4];
    if (lane == 63) wt[wid] = incl;
    __syncthreads();
    int woff = 0;
#pragma unroll
    for (int i = 0; i < 4; i++)
        if (i < wid) woff += wt[i];
    int run = bpre[blockIdx.x] + woff + (incl - s);
#pragma unroll
    for (int i = 0; i < 8; i++) {
        const int g = base + t * 8 + i;
        if (g < kM * kN) {
            const int m = g / kN;
            const int il = g - m * kN;
            offs[m * (kN + 1) + il] = run - m * kE;
            run += v[i];
        }
    }
}

// ---------------------------------------------------------------------------
// scatter src ids into CSR order, 4 edges per thread
__global__ void k_scatter(const int* __restrict__ ei, const int* __restrict__ offs,
                          int* __restrict__ cur, int* __restrict__ srcsort) {
    const int i = blockIdx.x * blockDim.x + threadIdx.x;
    if (i >= kM * kE / 4) return;
    const int m = i / (kE / 4);
    const int el4 = i - m * (kE / 4);
    const int4 s4 = *reinterpret_cast<const int4*>(ei + (size_t)m * 2 * kE + el4 * 4);
    const int4 d4 = *reinterpret_cast<const int4*>(ei + (size_t)m * 2 * kE + kE + el4 * 4);
    const int src[4] = {s4.x, s4.y, s4.z, s4.w};
    const int dst[4] = {d4.x, d4.y, d4.z, d4.w};
#pragma unroll
    for (int j = 0; j < 4; j++) {
        const int pos = offs[m * (kN + 1) + dst[j]] + atomicAdd(&cur[m * kN + dst[j]], 1);
        srcsort[(size_t)m * kE + pos] = src[j];
    }
}

// ---------------------------------------------------------------------------
// aggregation: per-dst block, wave m = metapath m. No max-shift softmax
// (shift-invariant, |logit| small). Cooperative per-(edge,head) weights via
// wave-local LDS broadcast. Full chunks branch-free (16 gathers in flight);
// tail clamps invalid slots to dst. 32-bit byte-offset addressing.
#define CH 16
__global__ __launch_bounds__(256) void k_agg(const unsigned short* __restrict__ h16,
                                             const float* __restrict__ sl,
                                             const float* __restrict__ sr,
                                             const int* __restrict__ offs,
                                             const int* __restrict__ srcsort,
                                             const float* __restrict__ ral,
                                             const float* __restrict__ rar,
                                             const float* __restrict__ rbias,
                                             float* __restrict__ out) {
    const int dst = blockIdx.x;
    const int t = threadIdx.x;
    const int m = t >> 6;
    const int l = t & 63;
    const int hh = l >> 4;        // head for this lane
    const int jj = l & 15;        // edge slot this lane computes the weight for
    const int e0 = l * 2;         // channel pair e0, e0+1

    __shared__ float smres[kM][kD];
    __shared__ float swts[kM][64];
    __shared__ int sids[kM][64];

    const int beg = offs[m * (kN + 1) + dst];
    const int cnt = offs[m * (kN + 1) + dst + 1] - beg;
    const float sl_h = sl[((size_t)m * kN + dst) * kH + hh];
    const int* __restrict__ sbase = srcsort + (size_t)m * kE + beg;
    const char* __restrict__ hb = (const char*)h16;
    const char* __restrict__ srb = (const char*)(sr + (size_t)m * kN * kH);
    const unsigned int ebyte = (unsigned int)(e0 << 1);
    const unsigned int hbyte = (unsigned int)(hh << 2);

    float sum = 0.f, a0 = 0.f, a1 = 0.f;
    const int cfull = cnt & ~(CH - 1);

    for (int c = 0; c < cfull; c += CH) {
        const int my = sbase[c + jj];
        sids[m][l] = my;
        const float srv = *reinterpret_cast<const float*>(
            srb + (((unsigned int)my << 4) + hbyte));
        __builtin_amdgcn_wave_barrier();
        int sj[CH];
        *reinterpret_cast<int4*>(&sj[0])  = *reinterpret_cast<const int4*>(&sids[m][0]);
        *reinterpret_cast<int4*>(&sj[4])  = *reinterpret_cast<const int4*>(&sids[m][4]);
        *reinterpret_cast<int4*>(&sj[8])  = *reinterpret_cast<const int4*>(&sids[m][8]);
        *reinterpret_cast<int4*>(&sj[12]) = *reinterpret_cast<const int4*>(&sids[m][12]);
        float x = sl_h + srv;
        x = x > 0.f ? x : 0.2f * x;            // LeakyReLU(0.2)
        const float w = __expf(x);
        sum += w;
        swts[m][l] = w;
        __builtin_amdgcn_wave_barrier();
        const float4 w0 = *reinterpret_cast<const float4*>(&swts[m][hh * 16]);
        const float4 w1 = *reinterpret_cast<const float4*>(&swts[m][hh * 16 + 4]);
        const float4 w2 = *reinterpret_cast<const float4*>(&swts[m][hh * 16 + 8]);
        const float4 w3 = *reinterpret_cast<const float4*>(&swts[m][hh * 16 + 12]);
        __builtin_amdgcn_wave_barrier();
        unsigned int u[CH];
#pragma unroll
        for (int j = 0; j < CH; j++)
            u[j] = *reinterpret_cast<const unsigned int*>(
                hb + (((unsigned int)sj[j] << 8) + ebyte));
        const float wj[CH] = {w0.x, w0.y, w0.z, w0.w, w1.x, w1.y, w1.z, w1.w,
                              w2.x, w2.y, w2.z, w2.w, w3.x, w3.y, w3.z, w3.w};
#pragma unroll
        for (int j = 0; j < CH; j++) {
            a0 += wj[j] * __uint_as_float(u[j] << 16);
            a1 += wj[j] * __uint_as_float(u[j] & 0xffff0000u);
        }
    }

    if (cfull < cnt) {
        const int c = cfull;
        const int my = sbase[c + jj];          // over-read lands in next segment / zeroed slack
        sids[m][l] = my;
        const float srv = *reinterpret_cast<const float*>(
            srb + (((unsigned int)my << 4) + hbyte));
        __builtin_amdgcn_wave_barrier();
        int sj[CH];
        *reinterpret_cast<int4*>(&sj[0])  = *reinterpret_cast<const int4*>(&sids[m][0]);
        *reinterpret_cast<int4*>(&sj[4])  = *reinterpret_cast<const int4*>(&sids[m][4]);
        *reinterpret_cast<int4*>(&sj[8])  = *reinterpret_cast<const int4*>(&sids[m][8]);
        *reinterpret_cast<int4*>(&sj[12]) = *reinterpret_cast<const int4*>(&sids[m][12]);
        float x = sl_h + srv;
        x = x > 0.f ? x : 0.2f * x;
        const float w = (c + jj < cnt) ? __expf(x) : 0.f;
        sum += w;
        swts[m][l] = w;
        __builtin_amdgcn_wave_barrier();
        const float4 w0 = *reinterpret_cast<const float4*>(&swts[m][hh * 16]);
        const float4 w1 = *reinterpret_cast<const float4*>(&swts[m][hh * 16 + 4]);
        const float4 w2 = *reinterpret_cast<const float4*>(&swts[m][hh * 16 + 8]);
        const float4 w3 = *reinterpret_cast<const float4*>(&swts[m][hh * 16 + 12]);
        __builtin_amdgcn_wave_barrier();
        const int nb = cnt - c;
#pragma unroll
        for (int j = 0; j < CH; j++) sj[j] = (j < nb) ? sj[j] : dst;
        unsigned int u[CH];
#pragma unroll
        for (int j = 0; j < CH; j++)
            u[j] = *reinterpret_cast<const unsigned int*>(
                hb + (((unsigned int)sj[j] << 8) + ebyte));
        const float wj[CH] = {w0.x, w0.y, w0.z, w0.w, w1.x, w1.y, w1.z, w1.w,
                              w2.x, w2.y, w2.z, w2.w, w3.x, w3.y, w3.z, w3.w};
#pragma unroll
        for (int j = 0; j < CH; j++) {
            a0 += wj[j] * __uint_as_float(u[j] << 16);
            a1 += wj[j] * __uint_as_float(u[j] & 0xffff0000u);
        }
    }

    sum += __shfl_xor(sum, 1);
    sum += __shfl_xor(sum, 2);
    sum += __shfl_xor(sum, 4);
    sum += __shfl_xor(sum, 8);
    const float inv = 1.0f / (sum + 1e-16f);
    smres[m][e0] = a0 * inv;
    smres[m][e0 + 1] = a1 * inv;
    __syncthreads();

    if (m == 0) {
        const unsigned int ud = *reinterpret_cast<const unsigned int*>(
            hb + (((unsigned int)dst << 8) + ebyte));
        const float hd0 = __uint_as_float(ud << 16);
        const float hd1 = __uint_as_float(ud & 0xffff0000u);
        const float bl0 = fmaxf(hd0 * ral[e0], 0.f);
        const float bl1 = fmaxf(hd1 * ral[e0 + 1], 0.f);
        float emb0[5], emb1[5], beta[5];
#pragma unroll
        for (int r = 0; r < 5; r++) {
            const float x0 = (r < 4) ? smres[r][e0] : hd0;
            const float x1 = (r < 4) ? smres[r][e0 + 1] : hd1;
            emb0[r] = x0;
            emb1[r] = x1;
            const float br0 = fmaxf(x0 * rar[r * kD + e0], 0.f);
            const float br1 = fmaxf(x1 * rar[r * kD + e0 + 1], 0.f);
            float p = bl0 * br0 + bl1 * br1;
            p += __shfl_xor(p, 1);
            p += __shfl_xor(p, 2);
            p += __shfl_xor(p, 4);
            p += __shfl_xor(p, 8);
            beta[r] = p + rbias[r];
        }
        float mx = beta[0];
#pragma unroll
        for (int r = 1; r < 5; r++) mx = fmaxf(mx, beta[r]);
        float s = 0.f, wgt[5];
#pragma unroll
        for (int r = 0; r < 5; r++) { wgt[r] = __expf(beta[r] - mx); s += wgt[r]; }
        const float invb = 1.f / s;
        float o0 = 0.f, o1 = 0.f;
#pragma unroll
        for (int r = 0; r < 5; r++) { o0 += emb0[r] * wgt[r]; o1 += emb1[r] * wgt[r]; }
        out[(size_t)dst * kD + e0] = fmaxf(o0 * invb, 0.f);
        out[(size_t)dst * kD + e0 + 1] = fmaxf(o1 * invb, 0.f);
    }
}

// ---------------------------------------------------------------------------
extern "C" void kernel_launch(void* const* d_in, const int* in_sizes, int n_in,
                              void* d_out, int out_size, void* d_ws, size_t ws_size,
                              hipStream_t stream) {
    const float* feats = (const float*)d_in[0];
    const int* ei      = (const int*)d_in[1];
    const float* W     = (const float*)d_in[2];
    const float* b     = (const float*)d_in[3];
    const float* attn  = (const float*)d_in[4];
    const float* ral   = (const float*)d_in[5];
    const float* rar   = (const float*)d_in[6];
    const float* rbias = (const float*)d_in[7];
    float* out = (float*)d_out;

    char* ws = (char*)d_ws;
    size_t off = 0;
    auto alloc = [&](size_t bytes) -> void* {
        void* p = ws + off;
        off = (off + bytes + 255) & ~(size_t)255;
        return p;
    };
    unsigned short* h16 = (unsigned short*)alloc(sizeof(short) * (size_t)kN * kD); // 12.8 MB
    unsigned short* Wt16= (unsigned short*)alloc(sizeof(short) * (size_t)kD * kIN); // 64 KB
    float* sl   = (float*)alloc(sizeof(float) * (size_t)kM * kN * kH);         // 3.2 MB
    float* sr   = (float*)alloc(sizeof(float) * (size_t)kM * kN * kH);         // 3.2 MB
    int* cnt    = (int*)alloc(sizeof(int) * (size_t)2 * kM * kN);              // cnt+cur
    int* cur    = cnt + (size_t)kM * kN;
    int* offs   = (int*)alloc(sizeof(int) * (size_t)kM * (kN + 1));
    int* srcsort= (int*)alloc(sizeof(int) * ((size_t)kM * kE + 64));           // + zeroed slack
    int* bsum   = (int*)alloc(sizeof(int) * SCBLOCKS);
    int* bpre   = (int*)alloc(sizeof(int) * 128);

    hipMemsetAsync(cnt, 0, sizeof(int) * (size_t)2 * kM * kN, stream);
    hipMemsetAsync(srcsort + (size_t)kM * kE, 0, sizeof(int) * 64, stream);
    k_wcast<<<kD, kIN, 0, stream>>>(W, Wt16);
    k_gemm<<<(kN + 127) / 128, 256, 0, stream>>>(feats, Wt16, b, h16);
    k_slr<<<(kN * kH + 255) / 256, 256, 0, stream>>>(h16, attn, sl, sr);
    k_count<<<(kM * kE / 4 + 255) / 256, 256, 0, stream>>>(ei, cnt);
    k_bsum<<<SCBLOCKS, 256, 0, stream>>>(cnt, bsum);
    k_bscan<<<1, 128, 0, stream>>>(bsum, bpre, offs);
    k_scanout<<<SCBLOCKS, 256, 0, stream>>>(cnt, bpre, offs);
    k_scatter<<<(kM * kE / 4 + 255) / 256, 256, 0, stream>>>(ei, offs, cur, srcsort);
    k_agg<<<kN, 256, 0, stream>>>(h16, sl, sr, offs, srcsort, ral, rar, rbias, out);
}

// Round 6
// 609.091 us; speedup vs baseline: 1.2675x; 1.0463x over previous
//
#include <hip/hip_runtime.h>
#include <math.h>

// Problem constants
#define kN 50000
#define kE 800000
#define kM 4
#define kH 4
#define kC 32
#define kIN 256
#define kD 128   // kH*kC

typedef __attribute__((ext_vector_type(8))) short bf16x8;
typedef __attribute__((ext_vector_type(4))) float f32x4;

__device__ __forceinline__ unsigned int f2bf_pack(float a, float b) {
    unsigned ua = __float_as_uint(a);
    ua += 0x7fffu + ((ua >> 16) & 1u);          // RNE
    unsigned ub = __float_as_uint(b);
    ub += 0x7fffu + ((ub >> 16) & 1u);
    return (ua >> 16) | (ub & 0xffff0000u);
}
__device__ __forceinline__ unsigned short f2bf(float x) {
    unsigned u = __float_as_uint(x);
    u += 0x7fffu + ((u >> 16) & 1u);
    return (unsigned short)(u >> 16);
}

// ---------------------------------------------------------------------------
// Wt16[col][k] = bf16(W[k][col])  (128 cols x 256 k)
__global__ void k_wcast(const float* __restrict__ W, unsigned short* __restrict__ Wt16) {
    const int col = blockIdx.x;        // 0..127
    const int k = threadIdx.x;         // 0..255
    Wt16[(size_t)col * kIN + k] = f2bf(W[(size_t)k * kD + col]);
}

// ---------------------------------------------------------------------------
// FUSED: blocks [0,GEMMB) = MFMA bf16 GEMM (h16 = relu(feats@W+b));
//        blocks [GEMMB, GEMMB+COUNTB) = CSR degree count (independent root).
// The count blocks' latency-bound atomics hide under the GEMM's MFMA time.
#define GEMMB ((kN + 127) / 128)          // 391
#define COUNTB (kM * kE / 4 / 256)        // 3125
__global__ __launch_bounds__(256) void k_gemmcount(const float* __restrict__ feats,
                                                   const unsigned short* __restrict__ Wt16,
                                                   const float* __restrict__ b,
                                                   unsigned short* __restrict__ h16,
                                                   const int* __restrict__ ei,
                                                   int* __restrict__ cnt) {
    __shared__ unsigned short fr16[128 * 32];   // 8 KB: A chunk [row][32k]
    const int t = threadIdx.x;

    if (blockIdx.x >= GEMMB) {
        // ---- degree count: 4 edges per thread via int4, fire-and-forget ----
        const int i = (blockIdx.x - GEMMB) * 256 + t;
        const int m = i / (kE / 4);
        const int el4 = i - m * (kE / 4);
        const int4 d = *reinterpret_cast<const int4*>(ei + (size_t)m * 2 * kE + kE + el4 * 4);
        atomicAdd(&cnt[m * kN + d.x], 1);
        atomicAdd(&cnt[m * kN + d.y], 1);
        atomicAdd(&cnt[m * kN + d.z], 1);
        atomicAdd(&cnt[m * kN + d.w], 1);
        return;
    }

    // ---- MFMA GEMM ----
    const int lane = t & 63;
    const int wave = t >> 6;
    const int q = lane >> 4;           // quad 0..3
    const int m16 = lane & 15;
    const int wrow = (wave >> 1) * 64;
    const int wcol = (wave & 1) * 64;
    const int rowbase = blockIdx.x * 128;

    f32x4 acc[4][4];
#pragma unroll
    for (int i = 0; i < 4; i++)
#pragma unroll
        for (int j = 0; j < 4; j++) acc[i][j] = (f32x4){0.f, 0.f, 0.f, 0.f};

    const int srow = t >> 3;           // staging: 32 rows per pass
    const int sk4 = t & 7;             // float4 slot along k (8 slots = 32 k)

    for (int kc = 0; kc < kIN; kc += 32) {
        __syncthreads();
#pragma unroll
        for (int it = 0; it < 4; it++) {
            const int row = srow + it * 32;
            const int rg = rowbase + row;
            float4 v = make_float4(0.f, 0.f, 0.f, 0.f);
            if (rg < kN)
                v = *reinterpret_cast<const float4*>(feats + (size_t)rg * kIN + kc + sk4 * 4);
            uint2 p;
            p.x = f2bf_pack(v.x, v.y);
            p.y = f2bf_pack(v.z, v.w);
            *reinterpret_cast<uint2*>(&fr16[row * 32 + sk4 * 4]) = p;
        }
        __syncthreads();

        bf16x8 afr[4], bfr[4];
#pragma unroll
        for (int ri = 0; ri < 4; ri++)
            afr[ri] = *reinterpret_cast<const bf16x8*>(
                &fr16[(wrow + ri * 16 + m16) * 32 + q * 8]);
#pragma unroll
        for (int ci = 0; ci < 4; ci++)
            bfr[ci] = *reinterpret_cast<const bf16x8*>(
                Wt16 + (size_t)(wcol + ci * 16 + m16) * kIN + kc + q * 8);
#pragma unroll
        for (int ri = 0; ri < 4; ri++)
#pragma unroll
            for (int ci = 0; ci < 4; ci++)
                acc[ri][ci] = __builtin_amdgcn_mfma_f32_16x16x32_bf16(
                    afr[ri], bfr[ci], acc[ri][ci], 0, 0, 0);
    }

    float bcol[4];
#pragma unroll
    for (int ci = 0; ci < 4; ci++) bcol[ci] = b[wcol + ci * 16 + m16];

#pragma unroll
    for (int ri = 0; ri < 4; ri++) {
#pragma unroll
        for (int reg = 0; reg < 4; reg++) {
            const int row = rowbase + wrow + ri * 16 + q * 4 + reg;
            if (row < kN) {
#pragma unroll
                for (int ci = 0; ci < 4; ci++) {
                    const int col = wcol + ci * 16 + m16;
                    const float v = fmaxf(acc[ri][ci][reg] + bcol[ci], 0.f);
                    h16[(size_t)row * kD + col] = f2bf(v);
                }
            }
        }
    }
}

// ---------------------------------------------------------------------------
// 3-phase parallel scan blocks
#define SCB 2048
#define SCBLOCKS ((kM * kN + SCB - 1) / SCB)   // 98

// FUSED: blocks [0,SLRB) = per-node attention scalars; [SLRB, SLRB+SCBLOCKS) = bsum.
#define SLRB ((kN * kH + 255) / 256)           // 782
__global__ __launch_bounds__(256) void k_slrsum(const unsigned short* __restrict__ h16,
                                                const float* __restrict__ attn,
                                                float* __restrict__ sl, float* __restrict__ sr,
                                                const int* __restrict__ cnt,
                                                int* __restrict__ bsum) {
    const int t = threadIdx.x;
    if (blockIdx.x >= SLRB) {
        // ---- bsum ----
        const int base = (blockIdx.x - SLRB) * SCB;
        int s = 0;
#pragma unroll
        for (int i = 0; i < 8; i++) {
            const int g = base + t * 8 + i;
            if (g < kM * kN) s += cnt[g];
        }
#pragma unroll
        for (int d = 1; d < 64; d <<= 1) s += __shfl_xor(s, d);
        __shared__ int ws[4];
        if ((t & 63) == 0) ws[t >> 6] = s;
        __syncthreads();
        if (t == 0) bsum[blockIdx.x - SLRB] = ws[0] + ws[1] + ws[2] + ws[3];
        return;
    }
    // ---- slr ----
    const int id = blockIdx.x * 256 + t;
    if (id >= kN * kH) return;
    const int n = id >> 2;
    const int hh = id & 3;
    const unsigned int* hu =
        reinterpret_cast<const unsigned int*>(h16 + (size_t)n * kD + hh * kC);
    unsigned int u[16];
    uint4 u4;
#pragma unroll
    for (int i = 0; i < 4; i++) {
        u4 = reinterpret_cast<const uint4*>(hu)[i];
        u[i * 4 + 0] = u4.x; u[i * 4 + 1] = u4.y; u[i * 4 + 2] = u4.z; u[i * 4 + 3] = u4.w;
    }
    float f0[16], f1[16];
#pragma unroll
    for (int c = 0; c < 16; c++) {
        f0[c] = __uint_as_float(u[c] << 16);
        f1[c] = __uint_as_float(u[c] & 0xffff0000u);
    }
#pragma unroll
    for (int m = 0; m < kM; m++) {
        const float2* al = reinterpret_cast<const float2*>(attn + (m * kH + hh) * 2 * kC);
        const float2* ar = al + 16;
        float s0 = 0.f, s1 = 0.f;
#pragma unroll
        for (int c = 0; c < 16; c++) {
            const float2 a = al[c], r = ar[c];
            s0 += f0[c] * a.x + f1[c] * a.y;
            s1 += f0[c] * r.x + f1[c] * r.y;
        }
        sl[((size_t)m * kN + n) * kH + hh] = s0;
        sr[((size_t)m * kN + n) * kH + hh] = s1;
    }
}

__global__ __launch_bounds__(128) void k_bscan(const int* __restrict__ bsum,
                                               int* __restrict__ bpre,
                                               int* __restrict__ offs) {
    const int t = threadIdx.x;
    const int lane = t & 63, wid = t >> 6;
    int v = (t < SCBLOCKS) ? bsum[t] : 0;
    int incl = v;
#pragma unroll
    for (int d = 1; d < 64; d <<= 1) {
        const int x = __shfl_up(incl, d);
        if (lane >= d) incl += x;
    }
    __shared__ int wt[2];
    if (lane == 63) wt[wid] = incl;
    __syncthreads();
    const int add = (wid == 1) ? wt[0] : 0;
    if (t < SCBLOCKS) bpre[t] = incl - v + add;
    if (t < kM) offs[t * (kN + 1) + kN] = kE;   // per-m sentinel
}

__global__ __launch_bounds__(256) void k_scanout(const int* __restrict__ cnt,
                                                 const int* __restrict__ bpre,
                                                 int* __restrict__ offs) {
    const int base = blockIdx.x * SCB;
    const int t = threadIdx.x;
    const int lane = t & 63, wid = t >> 6;
    int v[8];
    int s = 0;
#pragma unroll
    for (int i = 0; i < 8; i++) {
        const int g = base + t * 8 + i;
        v[i] = (g < kM * kN) ? cnt[g] : 0;
        s += v[i];
    }
    int incl = s;
#pragma unroll
    for (int d = 1; d < 64; d <<= 1) {
        const int x = __shfl_up(incl, d);
        if (lane >= d) incl += x;
    }
    __shared__ int wt[4];
    if (lane == 63) wt[wid] = incl;
    __syncthreads();
    int woff = 0;
#pragma unroll
    for (int i = 0; i < 4; i++)
        if (i < wid) woff += wt[i];
    int run = bpre[blockIdx.x] + woff + (incl - s);
#pragma unroll
    for (int i = 0; i < 8; i++) {
        const int g = base + t * 8 + i;
        if (g < kM * kN) {
            const int m = g / kN;
            const int il = g - m * kN;
            offs[m * (kN + 1) + il] = run - m * kE;
            run += v[i];
        }
    }
}

// ---------------------------------------------------------------------------
// sweep-partitioned scatter: sweep s (blockIdx.y) handles only edges whose
// dst is in [s*6250, (s+1)*6250) -> the scattered srcsort write window is
// ~0.8 MB per metapath (L2-resident), so lines fill before writeback
// (kills the 16x write amplification). Edge data is re-read per sweep but
// that's streaming traffic.
#define NSWEEP 8
#define SWRANGE (kN / NSWEEP)   // 6250
__global__ __launch_bounds__(256) void k_scatter(const int* __restrict__ ei,
                                                 const int* __restrict__ offs,
                                                 int* __restrict__ cur,
                                                 int* __restrict__ srcsort) {
    const int i = blockIdx.x * 256 + threadIdx.x;
    const int m = i / (kE / 4);
    const int el4 = i - m * (kE / 4);
    const int lo = blockIdx.y * SWRANGE;
    const int hi = lo + SWRANGE;
    const int4 s4 = *reinterpret_cast<const int4*>(ei + (size_t)m * 2 * kE + el4 * 4);
    const int4 d4 = *reinterpret_cast<const int4*>(ei + (size_t)m * 2 * kE + kE + el4 * 4);
    const int src[4] = {s4.x, s4.y, s4.z, s4.w};
    const int dst[4] = {d4.x, d4.y, d4.z, d4.w};
#pragma unroll
    for (int j = 0; j < 4; j++) {
        if (dst[j] >= lo && dst[j] < hi) {
            const int pos = offs[m * (kN + 1) + dst[j]] + atomicAdd(&cur[m * kN + dst[j]], 1);
            srcsort[(size_t)m * kE + pos] = src[j];
        }
    }
}

// ---------------------------------------------------------------------------
// aggregation: per-dst block, wave m = metapath m (unchanged from R5).
#define CH 16
__global__ __launch_bounds__(256) void k_agg(const unsigned short* __restrict__ h16,
                                             const float* __restrict__ sl,
                                             const float* __restrict__ sr,
                                             const int* __restrict__ offs,
                                             const int* __restrict__ srcsort,
                                             const float* __restrict__ ral,
                                             const float* __restrict__ rar,
                                             const float* __restrict__ rbias,
                                             float* __restrict__ out) {
    const int dst = blockIdx.x;
    const int t = threadIdx.x;
    const int m = t >> 6;
    const int l = t & 63;
    const int hh = l >> 4;        // head for this lane
    const int jj = l & 15;        // edge slot this lane computes the weight for
    const int e0 = l * 2;         // channel pair e0, e0+1

    __shared__ float smres[kM][kD];
    __shared__ float swts[kM][64];
    __shared__ int sids[kM][64];

    const int beg = offs[m * (kN + 1) + dst];
    const int cnt = offs[m * (kN + 1) + dst + 1] - beg;
    const float sl_h = sl[((size_t)m * kN + dst) * kH + hh];
    const int* __restrict__ sbase = srcsort + (size_t)m * kE + beg;
    const char* __restrict__ hb = (const char*)h16;
    const char* __restrict__ srb = (const char*)(sr + (size_t)m * kN * kH);
    const unsigned int ebyte = (unsigned int)(e0 << 1);
    const unsigned int hbyte = (unsigned int)(hh << 2);

    float sum = 0.f, a0 = 0.f, a1 = 0.f;
    const int cfull = cnt & ~(CH - 1);

    for (int c = 0; c < cfull; c += CH) {
        const int my = sbase[c + jj];
        sids[m][l] = my;
        const float srv = *reinterpret_cast<const float*>(
            srb + (((unsigned int)my << 4) + hbyte));
        __builtin_amdgcn_wave_barrier();
        int sj[CH];
        *reinterpret_cast<int4*>(&sj[0])  = *reinterpret_cast<const int4*>(&sids[m][0]);
        *reinterpret_cast<int4*>(&sj[4])  = *reinterpret_cast<const int4*>(&sids[m][4]);
        *reinterpret_cast<int4*>(&sj[8])  = *reinterpret_cast<const int4*>(&sids[m][8]);
        *reinterpret_cast<int4*>(&sj[12]) = *reinterpret_cast<const int4*>(&sids[m][12]);
        float x = sl_h + srv;
        x = x > 0.f ? x : 0.2f * x;            // LeakyReLU(0.2)
        const float w = __expf(x);
        sum += w;
        swts[m][l] = w;
        __builtin_amdgcn_wave_barrier();
        const float4 w0 = *reinterpret_cast<const float4*>(&swts[m][hh * 16]);
        const float4 w1 = *reinterpret_cast<const float4*>(&swts[m][hh * 16 + 4]);
        const float4 w2 = *reinterpret_cast<const float4*>(&swts[m][hh * 16 + 8]);
        const float4 w3 = *reinterpret_cast<const float4*>(&swts[m][hh * 16 + 12]);
        __builtin_amdgcn_wave_barrier();
        unsigned int u[CH];
#pragma unroll
        for (int j = 0; j < CH; j++)
            u[j] = *reinterpret_cast<const unsigned int*>(
                hb + (((unsigned int)sj[j] << 8) + ebyte));
        const float wj[CH] = {w0.x, w0.y, w0.z, w0.w, w1.x, w1.y, w1.z, w1.w,
                              w2.x, w2.y, w2.z, w2.w, w3.x, w3.y, w3.z, w3.w};
#pragma unroll
        for (int j = 0; j < CH; j++) {
            a0 += wj[j] * __uint_as_float(u[j] << 16);
            a1 += wj[j] * __uint_as_float(u[j] & 0xffff0000u);
        }
    }

    if (cfull < cnt) {
        const int c = cfull;
        const int my = sbase[c + jj];          // over-read lands in next segment / zeroed slack
        sids[m][l] = my;
        const float srv = *reinterpret_cast<const float*>(
            srb + (((unsigned int)my << 4) + hbyte));
        __builtin_amdgcn_wave_barrier();
        int sj[CH];
        *reinterpret_cast<int4*>(&sj[0])  = *reinterpret_cast<const int4*>(&sids[m][0]);
        *reinterpret_cast<int4*>(&sj[4])  = *reinterpret_cast<const int4*>(&sids[m][4]);
        *reinterpret_cast<int4*>(&sj[8])  = *reinterpret_cast<const int4*>(&sids[m][8]);
        *reinterpret_cast<int4*>(&sj[12]) = *reinterpret_cast<const int4*>(&sids[m][12]);
        float x = sl_h + srv;
        x = x > 0.f ? x : 0.2f * x;
        const float w = (c + jj < cnt) ? __expf(x) : 0.f;
        sum += w;
        swts[m][l] = w;
        __builtin_amdgcn_wave_barrier();
        const float4 w0 = *reinterpret_cast<const float4*>(&swts[m][hh * 16]);
        const float4 w1 = *reinterpret_cast<const float4*>(&swts[m][hh * 16 + 4]);
        const float4 w2 = *reinterpret_cast<const float4*>(&swts[m][hh * 16 + 8]);
        const float4 w3 = *reinterpret_cast<const float4*>(&swts[m][hh * 16 + 12]);
        __builtin_amdgcn_wave_barrier();
        const int nb = cnt - c;
#pragma unroll
        for (int j = 0; j < CH; j++) sj[j] = (j < nb) ? sj[j] : dst;
        unsigned int u[CH];
#pragma unroll
        for (int j = 0; j < CH; j++)
            u[j] = *reinterpret_cast<const unsigned int*>(
                hb + (((unsigned int)sj[j] << 8) + ebyte));
        const float wj[CH] = {w0.x, w0.y, w0.z, w0.w, w1.x, w1.y, w1.z, w1.w,
                              w2.x, w2.y, w2.z, w2.w, w3.x, w3.y, w3.z, w3.w};
#pragma unroll
        for (int j = 0; j < CH; j++) {
            a0 += wj[j] * __uint_as_float(u[j] << 16);
            a1 += wj[j] * __uint_as_float(u[j] & 0xffff0000u);
        }
    }

    sum += __shfl_xor(sum, 1);
    sum += __shfl_xor(sum, 2);
    sum += __shfl_xor(sum, 4);
    sum += __shfl_xor(sum, 8);
    const float inv = 1.0f / (sum + 1e-16f);
    smres[m][e0] = a0 * inv;
    smres[m][e0 + 1] = a1 * inv;
    __syncthreads();

    if (m == 0) {
        const unsigned int ud = *reinterpret_cast<const unsigned int*>(
            hb + (((unsigned int)dst << 8) + ebyte));
        const float hd0 = __uint_as_float(ud << 16);
        const float hd1 = __uint_as_float(ud & 0xffff0000u);
        const float bl0 = fmaxf(hd0 * ral[e0], 0.f);
        const float bl1 = fmaxf(hd1 * ral[e0 + 1], 0.f);
        float emb0[5], emb1[5], beta[5];
#pragma unroll
        for (int r = 0; r < 5; r++) {
            const float x0 = (r < 4) ? smres[r][e0] : hd0;
            const float x1 = (r < 4) ? smres[r][e0 + 1] : hd1;
            emb0[r] = x0;
            emb1[r] = x1;
            const float br0 = fmaxf(x0 * rar[r * kD + e0], 0.f);
            const float br1 = fmaxf(x1 * rar[r * kD + e0 + 1], 0.f);
            float p = bl0 * br0 + bl1 * br1;
            p += __shfl_xor(p, 1);
            p += __shfl_xor(p, 2);
            p += __shfl_xor(p, 4);
            p += __shfl_xor(p, 8);
            beta[r] = p + rbias[r];
        }
        float mx = beta[0];
#pragma unroll
        for (int r = 1; r < 5; r++) mx = fmaxf(mx, beta[r]);
        float s = 0.f, wgt[5];
#pragma unroll
        for (int r = 0; r < 5; r++) { wgt[r] = __expf(beta[r] - mx); s += wgt[r]; }
        const float invb = 1.f / s;
        float o0 = 0.f, o1 = 0.f;
#pragma unroll
        for (int r = 0; r < 5; r++) { o0 += emb0[r] * wgt[r]; o1 += emb1[r] * wgt[r]; }
        out[(size_t)dst * kD + e0] = fmaxf(o0 * invb, 0.f);
        out[(size_t)dst * kD + e0 + 1] = fmaxf(o1 * invb, 0.f);
    }
}

// ---------------------------------------------------------------------------
extern "C" void kernel_launch(void* const* d_in, const int* in_sizes, int n_in,
                              void* d_out, int out_size, void* d_ws, size_t ws_size,
                              hipStream_t stream) {
    const float* feats = (const float*)d_in[0];
    const int* ei      = (const int*)d_in[1];
    const float* W     = (const float*)d_in[2];
    const float* b     = (const float*)d_in[3];
    const float* attn  = (const float*)d_in[4];
    const float* ral   = (const float*)d_in[5];
    const float* rar   = (const float*)d_in[6];
    const float* rbias = (const float*)d_in[7];
    float* out = (float*)d_out;

    char* ws = (char*)d_ws;
    size_t off = 0;
    auto alloc = [&](size_t bytes) -> void* {
        void* p = ws + off;
        off = (off + bytes + 255) & ~(size_t)255;
        return p;
    };
    unsigned short* h16 = (unsigned short*)alloc(sizeof(short) * (size_t)kN * kD); // 12.8 MB
    unsigned short* Wt16= (unsigned short*)alloc(sizeof(short) * (size_t)kD * kIN); // 64 KB
    float* sl   = (float*)alloc(sizeof(float) * (size_t)kM * kN * kH);         // 3.2 MB
    float* sr   = (float*)alloc(sizeof(float) * (size_t)kM * kN * kH);         // 3.2 MB
    int* cnt    = (int*)alloc(sizeof(int) * (size_t)2 * kM * kN);              // cnt+cur
    int* cur    = cnt + (size_t)kM * kN;
    int* offs   = (int*)alloc(sizeof(int) * (size_t)kM * (kN + 1));
    int* srcsort= (int*)alloc(sizeof(int) * ((size_t)kM * kE + 64));           // + zeroed slack
    int* bsum   = (int*)alloc(sizeof(int) * SCBLOCKS);
    int* bpre   = (int*)alloc(sizeof(int) * 128);

    hipMemsetAsync(cnt, 0, sizeof(int) * (size_t)2 * kM * kN, stream);
    hipMemsetAsync(srcsort + (size_t)kM * kE, 0, sizeof(int) * 64, stream);
    k_wcast<<<kD, kIN, 0, stream>>>(W, Wt16);
    k_gemmcount<<<GEMMB + COUNTB, 256, 0, stream>>>(feats, Wt16, b, h16, ei, cnt);
    k_slrsum<<<SLRB + SCBLOCKS, 256, 0, stream>>>(h16, attn, sl, sr, cnt, bsum);
    k_bscan<<<1, 128, 0, stream>>>(bsum, bpre, offs);
    k_scanout<<<SCBLOCKS, 256, 0, stream>>>(cnt, bpre, offs);
    k_scatter<<<dim3(COUNTB, NSWEEP), 256, 0, stream>>>(ei, offs, cur, srcsort);
    k_agg<<<kN, 256, 0, stream>>>(h16, sl, sr, offs, srcsort, ral, rar, rbias, out);
}

// Round 7
// 583.436 us; speedup vs baseline: 1.3232x; 1.0440x over previous
//
#include <hip/hip_runtime.h>
#include <math.h>

// Problem constants
#define kN 50000
#define kE 800000
#define kM 4
#define kH 4
#define kC 32
#define kIN 256
#define kD 128   // kH*kC

typedef __attribute__((ext_vector_type(8))) short bf16x8;
typedef __attribute__((ext_vector_type(4))) float f32x4;

__device__ __forceinline__ unsigned int f2bf_pack(float a, float b) {
    unsigned ua = __float_as_uint(a);
    ua += 0x7fffu + ((ua >> 16) & 1u);          // RNE
    unsigned ub = __float_as_uint(b);
    ub += 0x7fffu + ((ub >> 16) & 1u);
    return (ua >> 16) | (ub & 0xffff0000u);
}
__device__ __forceinline__ unsigned short f2bf(float x) {
    unsigned u = __float_as_uint(x);
    u += 0x7fffu + ((u >> 16) & 1u);
    return (unsigned short)(u >> 16);
}

// ---------------------------------------------------------------------------
// Wt16[col][k] = bf16(W[k][col])  (128 cols x 256 k)
__global__ void k_wcast(const float* __restrict__ W, unsigned short* __restrict__ Wt16) {
    const int col = blockIdx.x;        // 0..127
    const int k = threadIdx.x;         // 0..255
    Wt16[(size_t)col * kIN + k] = f2bf(W[(size_t)k * kD + col]);
}

// ---------------------------------------------------------------------------
// FUSED: blocks [0,GEMMB) = MFMA bf16 GEMM (h16 = relu(feats@W+b));
//        blocks [GEMMB, GEMMB+COUNTB) = CSR degree count (independent root).
#define GEMMB ((kN + 127) / 128)          // 391
#define COUNTB (kM * kE / 4 / 256)        // 3125
__global__ __launch_bounds__(256) void k_gemmcount(const float* __restrict__ feats,
                                                   const unsigned short* __restrict__ Wt16,
                                                   const float* __restrict__ b,
                                                   unsigned short* __restrict__ h16,
                                                   const int* __restrict__ ei,
                                                   int* __restrict__ cnt) {
    __shared__ unsigned short fr16[128 * 32];   // 8 KB: A chunk [row][32k]
    const int t = threadIdx.x;

    if (blockIdx.x >= GEMMB) {
        // ---- degree count: 4 edges per thread via int4 ----
        const int i = (blockIdx.x - GEMMB) * 256 + t;
        const int m = i / (kE / 4);
        const int el4 = i - m * (kE / 4);
        const int4 d = *reinterpret_cast<const int4*>(ei + (size_t)m * 2 * kE + kE + el4 * 4);
        atomicAdd(&cnt[m * kN + d.x], 1);
        atomicAdd(&cnt[m * kN + d.y], 1);
        atomicAdd(&cnt[m * kN + d.z], 1);
        atomicAdd(&cnt[m * kN + d.w], 1);
        return;
    }

    // ---- MFMA GEMM ----
    const int lane = t & 63;
    const int wave = t >> 6;
    const int q = lane >> 4;           // quad 0..3
    const int m16 = lane & 15;
    const int wrow = (wave >> 1) * 64;
    const int wcol = (wave & 1) * 64;
    const int rowbase = blockIdx.x * 128;

    f32x4 acc[4][4];
#pragma unroll
    for (int i = 0; i < 4; i++)
#pragma unroll
        for (int j = 0; j < 4; j++) acc[i][j] = (f32x4){0.f, 0.f, 0.f, 0.f};

    const int srow = t >> 3;           // staging: 32 rows per pass
    const int sk4 = t & 7;             // float4 slot along k (8 slots = 32 k)

    for (int kc = 0; kc < kIN; kc += 32) {
        __syncthreads();
#pragma unroll
        for (int it = 0; it < 4; it++) {
            const int row = srow + it * 32;
            const int rg = rowbase + row;
            float4 v = make_float4(0.f, 0.f, 0.f, 0.f);
            if (rg < kN)
                v = *reinterpret_cast<const float4*>(feats + (size_t)rg * kIN + kc + sk4 * 4);
            uint2 p;
            p.x = f2bf_pack(v.x, v.y);
            p.y = f2bf_pack(v.z, v.w);
            *reinterpret_cast<uint2*>(&fr16[row * 32 + sk4 * 4]) = p;
        }
        __syncthreads();

        bf16x8 afr[4], bfr[4];
#pragma unroll
        for (int ri = 0; ri < 4; ri++)
            afr[ri] = *reinterpret_cast<const bf16x8*>(
                &fr16[(wrow + ri * 16 + m16) * 32 + q * 8]);
#pragma unroll
        for (int ci = 0; ci < 4; ci++)
            bfr[ci] = *reinterpret_cast<const bf16x8*>(
                Wt16 + (size_t)(wcol + ci * 16 + m16) * kIN + kc + q * 8);
#pragma unroll
        for (int ri = 0; ri < 4; ri++)
#pragma unroll
            for (int ci = 0; ci < 4; ci++)
                acc[ri][ci] = __builtin_amdgcn_mfma_f32_16x16x32_bf16(
                    afr[ri], bfr[ci], acc[ri][ci], 0, 0, 0);
    }

    float bcol[4];
#pragma unroll
    for (int ci = 0; ci < 4; ci++) bcol[ci] = b[wcol + ci * 16 + m16];

#pragma unroll
    for (int ri = 0; ri < 4; ri++) {
#pragma unroll
        for (int reg = 0; reg < 4; reg++) {
            const int row = rowbase + wrow + ri * 16 + q * 4 + reg;
            if (row < kN) {
#pragma unroll
                for (int ci = 0; ci < 4; ci++) {
                    const int col = wcol + ci * 16 + m16;
                    const float v = fmaxf(acc[ri][ci][reg] + bcol[ci], 0.f);
                    h16[(size_t)row * kD + col] = f2bf(v);
                }
            }
        }
    }
}

// ---------------------------------------------------------------------------
// 3-phase parallel scan blocks
#define SCB 2048
#define SCBLOCKS ((kM * kN + SCB - 1) / SCB)   // 98

// FUSED: blocks [0,SLRB) = per-node attention scalars; [SLRB, SLRB+SCBLOCKS) = bsum.
#define SLRB ((kN * kH + 255) / 256)           // 782
__global__ __launch_bounds__(256) void k_slrsum(const unsigned short* __restrict__ h16,
                                                const float* __restrict__ attn,
                                                float* __restrict__ sl, float* __restrict__ sr,
                                                const int* __restrict__ cnt,
                                                int* __restrict__ bsum) {
    const int t = threadIdx.x;
    if (blockIdx.x >= SLRB) {
        // ---- bsum ----
        const int base = (blockIdx.x - SLRB) * SCB;
        int s = 0;
#pragma unroll
        for (int i = 0; i < 8; i++) {
            const int g = base + t * 8 + i;
            if (g < kM * kN) s += cnt[g];
        }
#pragma unroll
        for (int d = 1; d < 64; d <<= 1) s += __shfl_xor(s, d);
        __shared__ int ws[4];
        if ((t & 63) == 0) ws[t >> 6] = s;
        __syncthreads();
        if (t == 0) bsum[blockIdx.x - SLRB] = ws[0] + ws[1] + ws[2] + ws[3];
        return;
    }
    // ---- slr ----
    const int id = blockIdx.x * 256 + t;
    if (id >= kN * kH) return;
    const int n = id >> 2;
    const int hh = id & 3;
    const unsigned int* hu =
        reinterpret_cast<const unsigned int*>(h16 + (size_t)n * kD + hh * kC);
    unsigned int u[16];
    uint4 u4;
#pragma unroll
    for (int i = 0; i < 4; i++) {
        u4 = reinterpret_cast<const uint4*>(hu)[i];
        u[i * 4 + 0] = u4.x; u[i * 4 + 1] = u4.y; u[i * 4 + 2] = u4.z; u[i * 4 + 3] = u4.w;
    }
    float f0[16], f1[16];
#pragma unroll
    for (int c = 0; c < 16; c++) {
        f0[c] = __uint_as_float(u[c] << 16);
        f1[c] = __uint_as_float(u[c] & 0xffff0000u);
    }
#pragma unroll
    for (int m = 0; m < kM; m++) {
        const float2* al = reinterpret_cast<const float2*>(attn + (m * kH + hh) * 2 * kC);
        const float2* ar = al + 16;
        float s0 = 0.f, s1 = 0.f;
#pragma unroll
        for (int c = 0; c < 16; c++) {
            const float2 a = al[c], r = ar[c];
            s0 += f0[c] * a.x + f1[c] * a.y;
            s1 += f0[c] * r.x + f1[c] * r.y;
        }
        sl[((size_t)m * kN + n) * kH + hh] = s0;
        sr[((size_t)m * kN + n) * kH + hh] = s1;
    }
}

__global__ __launch_bounds__(128) void k_bscan(const int* __restrict__ bsum,
                                               int* __restrict__ bpre,
                                               int* __restrict__ offs) {
    const int t = threadIdx.x;
    const int lane = t & 63, wid = t >> 6;
    int v = (t < SCBLOCKS) ? bsum[t] : 0;
    int incl = v;
#pragma unroll
    for (int d = 1; d < 64; d <<= 1) {
        const int x = __shfl_up(incl, d);
        if (lane >= d) incl += x;
    }
    __shared__ int wt[2];
    if (lane == 63) wt[wid] = incl;
    __syncthreads();
    const int add = (wid == 1) ? wt[0] : 0;
    if (t < SCBLOCKS) bpre[t] = incl - v + add;
    if (t < kM) offs[t * (kN + 1) + kN] = kE;   // per-m sentinel
}

__global__ __launch_bounds__(256) void k_scanout(const int* __restrict__ cnt,
                                                 const int* __restrict__ bpre,
                                                 int* __restrict__ offs) {
    const int base = blockIdx.x * SCB;
    const int t = threadIdx.x;
    const int lane = t & 63, wid = t >> 6;
    int v[8];
    int s = 0;
#pragma unroll
    for (int i = 0; i < 8; i++) {
        const int g = base + t * 8 + i;
        v[i] = (g < kM * kN) ? cnt[g] : 0;
        s += v[i];
    }
    int incl = s;
#pragma unroll
    for (int d = 1; d < 64; d <<= 1) {
        const int x = __shfl_up(incl, d);
        if (lane >= d) incl += x;
    }
    __shared__ int wt[4];
    if (lane == 63) wt[wid] = incl;
    __syncthreads();
    int woff = 0;
#pragma unroll
    for (int i = 0; i < 4; i++)
        if (i < wid) woff += wt[i];
    int run = bpre[blockIdx.x] + woff + (incl - s);
#pragma unroll
    for (int i = 0; i < 8; i++) {
        const int g = base + t * 8 + i;
        if (g < kM * kN) {
            const int m = g / kN;
            const int il = g - m * kN;
            offs[m * (kN + 1) + il] = run - m * kE;
            run += v[i];
        }
    }
}

// ---------------------------------------------------------------------------
// XCD-affine partitioned scatter. partition = blockIdx.x (FASTEST grid dim):
// the dispatcher round-robins linearized block ids over the 8 XCDs, so all
// blocks handling dst-partition p land (heuristically) on XCD p. All writes
// to a given srcsort line then come from ONE XCD's L2 -> lines are fully
// assembled before writeback (R6 showed cross-XCD line-splitting caused 14x
// write amplification). Correctness does not depend on the XCD mapping:
// each (partition, chunk) pair is processed exactly once by construction.
#define NSWEEP 8
#define SWRANGE (kN / NSWEEP)   // 6250
__global__ __launch_bounds__(256) void k_scatter(const int* __restrict__ ei,
                                                 const int* __restrict__ offs,
                                                 int* __restrict__ cur,
                                                 int* __restrict__ srcsort) {
    const int i = blockIdx.y * 256 + threadIdx.x;
    const int m = i / (kE / 4);
    const int el4 = i - m * (kE / 4);
    const int lo = blockIdx.x * SWRANGE;
    const int hi = lo + SWRANGE;
    const int4 s4 = *reinterpret_cast<const int4*>(ei + (size_t)m * 2 * kE + el4 * 4);
    const int4 d4 = *reinterpret_cast<const int4*>(ei + (size_t)m * 2 * kE + kE + el4 * 4);
    const int src[4] = {s4.x, s4.y, s4.z, s4.w};
    const int dst[4] = {d4.x, d4.y, d4.z, d4.w};
#pragma unroll
    for (int j = 0; j < 4; j++) {
        if (dst[j] >= lo && dst[j] < hi) {
            const int pos = offs[m * (kN + 1) + dst[j]] + atomicAdd(&cur[m * kN + dst[j]], 1);
            srcsort[(size_t)m * kE + pos] = src[j];
        }
    }
}

// ---------------------------------------------------------------------------
// aggregation: per-dst block, wave m = metapath m (unchanged).
#define CH 16
__global__ __launch_bounds__(256) void k_agg(const unsigned short* __restrict__ h16,
                                             const float* __restrict__ sl,
                                             const float* __restrict__ sr,
                                             const int* __restrict__ offs,
                                             const int* __restrict__ srcsort,
                                             const float* __restrict__ ral,
                                             const float* __restrict__ rar,
                                             const float* __restrict__ rbias,
                                             float* __restrict__ out) {
    const int dst = blockIdx.x;
    const int t = threadIdx.x;
    const int m = t >> 6;
    const int l = t & 63;
    const int hh = l >> 4;        // head for this lane
    const int jj = l & 15;        // edge slot this lane computes the weight for
    const int e0 = l * 2;         // channel pair e0, e0+1

    __shared__ float smres[kM][kD];
    __shared__ float swts[kM][64];
    __shared__ int sids[kM][64];

    const int beg = offs[m * (kN + 1) + dst];
    const int cnt = offs[m * (kN + 1) + dst + 1] - beg;
    const float sl_h = sl[((size_t)m * kN + dst) * kH + hh];
    const int* __restrict__ sbase = srcsort + (size_t)m * kE + beg;
    const char* __restrict__ hb = (const char*)h16;
    const char* __restrict__ srb = (const char*)(sr + (size_t)m * kN * kH);
    const unsigned int ebyte = (unsigned int)(e0 << 1);
    const unsigned int hbyte = (unsigned int)(hh << 2);

    float sum = 0.f, a0 = 0.f, a1 = 0.f;
    const int cfull = cnt & ~(CH - 1);

    for (int c = 0; c < cfull; c += CH) {
        const int my = sbase[c + jj];
        sids[m][l] = my;
        const float srv = *reinterpret_cast<const float*>(
            srb + (((unsigned int)my << 4) + hbyte));
        __builtin_amdgcn_wave_barrier();
        int sj[CH];
        *reinterpret_cast<int4*>(&sj[0])  = *reinterpret_cast<const int4*>(&sids[m][0]);
        *reinterpret_cast<int4*>(&sj[4])  = *reinterpret_cast<const int4*>(&sids[m][4]);
        *reinterpret_cast<int4*>(&sj[8])  = *reinterpret_cast<const int4*>(&sids[m][8]);
        *reinterpret_cast<int4*>(&sj[12]) = *reinterpret_cast<const int4*>(&sids[m][12]);
        float x = sl_h + srv;
        x = x > 0.f ? x : 0.2f * x;            // LeakyReLU(0.2)
        const float w = __expf(x);
        sum += w;
        swts[m][l] = w;
        __builtin_amdgcn_wave_barrier();
        const float4 w0 = *reinterpret_cast<const float4*>(&swts[m][hh * 16]);
        const float4 w1 = *reinterpret_cast<const float4*>(&swts[m][hh * 16 + 4]);
        const float4 w2 = *reinterpret_cast<const float4*>(&swts[m][hh * 16 + 8]);
        const float4 w3 = *reinterpret_cast<const float4*>(&swts[m][hh * 16 + 12]);
        __builtin_amdgcn_wave_barrier();
        unsigned int u[CH];
#pragma unroll
        for (int j = 0; j < CH; j++)
            u[j] = *reinterpret_cast<const unsigned int*>(
                hb + (((unsigned int)sj[j] << 8) + ebyte));
        const float wj[CH] = {w0.x, w0.y, w0.z, w0.w, w1.x, w1.y, w1.z, w1.w,
                              w2.x, w2.y, w2.z, w2.w, w3.x, w3.y, w3.z, w3.w};
#pragma unroll
        for (int j = 0; j < CH; j++) {
            a0 += wj[j] * __uint_as_float(u[j] << 16);
            a1 += wj[j] * __uint_as_float(u[j] & 0xffff0000u);
        }
    }

    if (cfull < cnt) {
        const int c = cfull;
        const int my = sbase[c + jj];          // over-read lands in next segment / zeroed slack
        sids[m][l] = my;
        const float srv = *reinterpret_cast<const float*>(
            srb + (((unsigned int)my << 4) + hbyte));
        __builtin_amdgcn_wave_barrier();
        int sj[CH];
        *reinterpret_cast<int4*>(&sj[0])  = *reinterpret_cast<const int4*>(&sids[m][0]);
        *reinterpret_cast<int4*>(&sj[4])  = *reinterpret_cast<const int4*>(&sids[m][4]);
        *reinterpret_cast<int4*>(&sj[8])  = *reinterpret_cast<const int4*>(&sids[m][8]);
        *reinterpret_cast<int4*>(&sj[12]) = *reinterpret_cast<const int4*>(&sids[m][12]);
        float x = sl_h + srv;
        x = x > 0.f ? x : 0.2f * x;
        const float w = (c + jj < cnt) ? __expf(x) : 0.f;
        sum += w;
        swts[m][l] = w;
        __builtin_amdgcn_wave_barrier();
        const float4 w0 = *reinterpret_cast<const float4*>(&swts[m][hh * 16]);
        const float4 w1 = *reinterpret_cast<const float4*>(&swts[m][hh * 16 + 4]);
        const float4 w2 = *reinterpret_cast<const float4*>(&swts[m][hh * 16 + 8]);
        const float4 w3 = *reinterpret_cast<const float4*>(&swts[m][hh * 16 + 12]);
        __builtin_amdgcn_wave_barrier();
        const int nb = cnt - c;
#pragma unroll
        for (int j = 0; j < CH; j++) sj[j] = (j < nb) ? sj[j] : dst;
        unsigned int u[CH];
#pragma unroll
        for (int j = 0; j < CH; j++)
            u[j] = *reinterpret_cast<const unsigned int*>(
                hb + (((unsigned int)sj[j] << 8) + ebyte));
        const float wj[CH] = {w0.x, w0.y, w0.z, w0.w, w1.x, w1.y, w1.z, w1.w,
                              w2.x, w2.y, w2.z, w2.w, w3.x, w3.y, w3.z, w3.w};
#pragma unroll
        for (int j = 0; j < CH; j++) {
            a0 += wj[j] * __uint_as_float(u[j] << 16);
            a1 += wj[j] * __uint_as_float(u[j] & 0xffff0000u);
        }
    }

    sum += __shfl_xor(sum, 1);
    sum += __shfl_xor(sum, 2);
    sum += __shfl_xor(sum, 4);
    sum += __shfl_xor(sum, 8);
    const float inv = 1.0f / (sum + 1e-16f);
    smres[m][e0] = a0 * inv;
    smres[m][e0 + 1] = a1 * inv;
    __syncthreads();

    if (m == 0) {
        const unsigned int ud = *reinterpret_cast<const unsigned int*>(
            hb + (((unsigned int)dst << 8) + ebyte));
        const float hd0 = __uint_as_float(ud << 16);
        const float hd1 = __uint_as_float(ud & 0xffff0000u);
        const float bl0 = fmaxf(hd0 * ral[e0], 0.f);
        const float bl1 = fmaxf(hd1 * ral[e0 + 1], 0.f);
        float emb0[5], emb1[5], beta[5];
#pragma unroll
        for (int r = 0; r < 5; r++) {
            const float x0 = (r < 4) ? smres[r][e0] : hd0;
            const float x1 = (r < 4) ? smres[r][e0 + 1] : hd1;
            emb0[r] = x0;
            emb1[r] = x1;
            const float br0 = fmaxf(x0 * rar[r * kD + e0], 0.f);
            const float br1 = fmaxf(x1 * rar[r * kD + e0 + 1], 0.f);
            float p = bl0 * br0 + bl1 * br1;
            p += __shfl_xor(p, 1);
            p += __shfl_xor(p, 2);
            p += __shfl_xor(p, 4);
            p += __shfl_xor(p, 8);
            beta[r] = p + rbias[r];
        }
        float mx = beta[0];
#pragma unroll
        for (int r = 1; r < 5; r++) mx = fmaxf(mx, beta[r]);
        float s = 0.f, wgt[5];
#pragma unroll
        for (int r = 0; r < 5; r++) { wgt[r] = __expf(beta[r] - mx); s += wgt[r]; }
        const float invb = 1.f / s;
        float o0 = 0.f, o1 = 0.f;
#pragma unroll
        for (int r = 0; r < 5; r++) { o0 += emb0[r] * wgt[r]; o1 += emb1[r] * wgt[r]; }
        out[(size_t)dst * kD + e0] = fmaxf(o0 * invb, 0.f);
        out[(size_t)dst * kD + e0 + 1] = fmaxf(o1 * invb, 0.f);
    }
}

// ---------------------------------------------------------------------------
extern "C" void kernel_launch(void* const* d_in, const int* in_sizes, int n_in,
                              void* d_out, int out_size, void* d_ws, size_t ws_size,
                              hipStream_t stream) {
    const float* feats = (const float*)d_in[0];
    const int* ei      = (const int*)d_in[1];
    const float* W     = (const float*)d_in[2];
    const float* b     = (const float*)d_in[3];
    const float* attn  = (const float*)d_in[4];
    const float* ral   = (const float*)d_in[5];
    const float* rar   = (const float*)d_in[6];
    const float* rbias = (const float*)d_in[7];
    float* out = (float*)d_out;

    char* ws = (char*)d_ws;
    size_t off = 0;
    auto alloc = [&](size_t bytes) -> void* {
        void* p = ws + off;
        off = (off + bytes + 255) & ~(size_t)255;
        return p;
    };
    unsigned short* h16 = (unsigned short*)alloc(sizeof(short) * (size_t)kN * kD); // 12.8 MB
    unsigned short* Wt16= (unsigned short*)alloc(sizeof(short) * (size_t)kD * kIN); // 64 KB
    float* sl   = (float*)alloc(sizeof(float) * (size_t)kM * kN * kH);         // 3.2 MB
    float* sr   = (float*)alloc(sizeof(float) * (size_t)kM * kN * kH);         // 3.2 MB
    int* cnt    = (int*)alloc(sizeof(int) * (size_t)2 * kM * kN);              // cnt+cur
    int* cur    = cnt + (size_t)kM * kN;
    int* offs   = (int*)alloc(sizeof(int) * (size_t)kM * (kN + 1));
    int* srcsort= (int*)alloc(sizeof(int) * ((size_t)kM * kE + 64));           // + zeroed slack
    int* bsum   = (int*)alloc(sizeof(int) * SCBLOCKS);
    int* bpre   = (int*)alloc(sizeof(int) * 128);

    hipMemsetAsync(cnt, 0, sizeof(int) * (size_t)2 * kM * kN, stream);
    hipMemsetAsync(srcsort + (size_t)kM * kE, 0, sizeof(int) * 64, stream);
    k_wcast<<<kD, kIN, 0, stream>>>(W, Wt16);
    k_gemmcount<<<GEMMB + COUNTB, 256, 0, stream>>>(feats, Wt16, b, h16, ei, cnt);
    k_slrsum<<<SLRB + SCBLOCKS, 256, 0, stream>>>(h16, attn, sl, sr, cnt, bsum);
    k_bscan<<<1, 128, 0, stream>>>(bsum, bpre, offs);
    k_scanout<<<SCBLOCKS, 256, 0, stream>>>(cnt, bpre, offs);
    k_scatter<<<dim3(NSWEEP, COUNTB), 256, 0, stream>>>(ei, offs, cur, srcsort);
    k_agg<<<kN, 256, 0, stream>>>(h16, sl, sr, offs, srcsort, ral, rar, rbias, out);
}